// Round 14
// baseline (588.121 us; speedup 1.0000x reference)
//
#include <hip/hip_runtime.h>

// Problem constants
constexpr int S = 8, B = 128, T = 256, N = 128;
constexpr int L = 64, Hh = 128, Hd = 64, Hl = 128;
constexpr int BT = B * T;

#define DEVFN __device__ __forceinline__

typedef float    f32x4_t __attribute__((ext_vector_type(4)));
typedef _Float16 f16x8_t __attribute__((ext_vector_type(8)));
typedef _Float16 f16x4_t __attribute__((ext_vector_type(4)));

DEVFN float softplus_f(float x) {            // accurate (prologue only)
    return (x > 0.f) ? (x + log1pf(expf(-x))) : log1pf(expf(x));
}
DEVFN float softplus_fast(float x) {         // branchless, native trans
    return fmaxf(x, 0.f) + __logf(1.f + __expf(-fabsf(x)));
}
DEVFN float fast_tanh(float x) {
    float ex = __builtin_exp2f(x * 2.885390081777927f);
    return 1.f - 2.f / (ex + 1.f);
}
DEVFN float gaOf(float yv) {                 // gammaln(y+1), y in {0..4}
    int yi = (int)yv;
    return (yi < 2) ? 0.f
         : ((yi == 2) ? 0.6931471805599453f
         : ((yi == 3) ? 1.791759469228055f : 3.1780538303479458f));
}

// ---------------------------------------------------------------------------
// Kernel A (MFMA): per (b,t) row: h = tanh(y@W_be + b_be); A = h@W1a + b_le1.
// ---------------------------------------------------------------------------
__global__ __launch_bounds__(256) void kA(
        const float* __restrict__ y,
        const float* __restrict__ W_be, const float* __restrict__ b_be,
        const float* __restrict__ W_le1, const float* __restrict__ b_le1,
        float* __restrict__ A, float* __restrict__ h0) {
    __shared__ alignas(16) _Float16 yS[32][136];   // [row][n] pad 68 dw
    __shared__ alignas(16) _Float16 hS[32][152];   // pad 76 dw
    __shared__ alignas(16) float    st[32][136];   // f32 acc staging
    __shared__ float bbeS[128];

    const int tid = threadIdx.x;
    const int w = tid >> 6, l = tid & 63;
    const int lo = l & 15, hi = l >> 4;
    const int bt0 = blockIdx.x * 32;

    if (tid < 128) bbeS[tid] = b_be[tid];

    // ---- load y rows -> f16 LDS ----
    {
        const float4* y4 = (const float4*)(y + (size_t)bt0 * 128);
        #pragma unroll
        for (int k = 0; k < 4; ++k) {
            int i = k * 256 + tid;              // 1024 float4s
            float4 v = y4[i];
            int row = i >> 5, c4 = (i & 31) * 4;
            f16x4_t h4;
            h4[0] = (_Float16)v.x; h4[1] = (_Float16)v.y;
            h4[2] = (_Float16)v.z; h4[3] = (_Float16)v.w;
            *(f16x4_t*)&yS[row][c4] = h4;
        }
    }

    // ---- weight fragments (64 VGPRs) ----
    f16x8_t awb[2][4], awa[2][4];
    #pragma unroll
    for (int ct = 0; ct < 2; ++ct)
        #pragma unroll
        for (int kt = 0; kt < 4; ++kt) {
            f16x8_t f, g;
            #pragma unroll
            for (int e = 0; e < 8; ++e) {
                size_t off = (size_t)(kt * 32 + 8 * hi + e) * 128 + (32 * w + 16 * ct + lo);
                f[e] = (_Float16)W_be[off];
                g[e] = (_Float16)W_le1[off];    // rows 0..127 = W1a
            }
            awb[ct][kt] = f; awa[ct][kt] = g;
        }
    const f32x4_t bl0 = *(const f32x4_t*)&b_le1[32 * w + 4 * hi];
    const f32x4_t bl1 = *(const f32x4_t*)&b_le1[32 * w + 16 + 4 * hi];
    __syncthreads();

    // ---- GEMM1: h_pre = y @ W_be ----
    #pragma unroll
    for (int rt = 0; rt < 2; ++rt) {
        f32x4_t acc0 = {0.f,0.f,0.f,0.f}, acc1 = {0.f,0.f,0.f,0.f};
        #pragma unroll
        for (int kt = 0; kt < 4; ++kt) {
            const f16x8_t bf = *(const f16x8_t*)&yS[16 * rt + lo][kt * 32 + 8 * hi];
            acc0 = __builtin_amdgcn_mfma_f32_16x16x32_f16(awb[0][kt], bf, acc0, 0, 0, 0);
            acc1 = __builtin_amdgcn_mfma_f32_16x16x32_f16(awb[1][kt], bf, acc1, 0, 0, 0);
        }
        *(f32x4_t*)&st[16 * rt + lo][32 * w + 4 * hi]      = acc0;
        *(f32x4_t*)&st[16 * rt + lo][32 * w + 16 + 4 * hi] = acc1;
    }
    __syncthreads();

    // ---- dense tanh pass: 16 values/thread ----
    {
        const int trow = tid >> 3, cb = (tid & 7) * 16;
        const bool isH0 = ((bt0 & 255) == 0) && (trow == 0);
        float* h0p = h0 + (size_t)(bt0 >> 8) * 128;
        #pragma unroll
        for (int j = 0; j < 16; ++j) {
            float hv = fast_tanh(st[trow][cb + j] + bbeS[cb + j]);
            hS[trow][cb + j] = (_Float16)hv;
            if (isH0) h0p[cb + j] = hv;
        }
    }
    __syncthreads();

    // ---- GEMM2: A = h @ W1a + b_le1 ----
    #pragma unroll
    for (int rt = 0; rt < 2; ++rt) {
        f32x4_t acc0 = {0.f,0.f,0.f,0.f}, acc1 = {0.f,0.f,0.f,0.f};
        #pragma unroll
        for (int kt = 0; kt < 4; ++kt) {
            const f16x8_t bf = *(const f16x8_t*)&hS[16 * rt + lo][kt * 32 + 8 * hi];
            acc0 = __builtin_amdgcn_mfma_f32_16x16x32_f16(awa[0][kt], bf, acc0, 0, 0, 0);
            acc1 = __builtin_amdgcn_mfma_f32_16x16x32_f16(awa[1][kt], bf, acc1, 0, 0, 0);
        }
        acc0 += bl0; acc1 += bl1;
        float* Ar = A + (size_t)(bt0 + 16 * rt + lo) * 128;
        *(f32x4_t*)&Ar[32 * w + 4 * hi]      = acc0;
        *(f32x4_t*)&Ar[32 * w + 16 + 4 * hi] = acc1;
    }
}

// ---------------------------------------------------------------------------
// Kernel B: initial step (t=0). Writes kl0[b] scalar.
// ---------------------------------------------------------------------------
__global__ __launch_bounds__(128) void kB(
        const float* __restrict__ h0, const float* __restrict__ W_ic,
        const float* __restrict__ b_ic, const float* __restrict__ m_0,
        const float* __restrict__ log_Q_0, const float* __restrict__ eps0,
        float* __restrict__ zout, float* __restrict__ kl0w) {
    __shared__ float hr[128];
    __shared__ float mp[128];
    const int b = blockIdx.x, tid = threadIdx.x;
    hr[tid] = h0[b * 128 + tid];
    __syncthreads();
    float acc = b_ic[tid];
    #pragma unroll 8
    for (int k = 0; k < 128; k++) acc += hr[k] * W_ic[k * 128 + tid];
    mp[tid] = acc;
    __syncthreads();

    float term = 0.f;
    if (tid < 64) {
        float m = mp[tid];
        float P = softplus_f(mp[tid + 64]);
        float sq = sqrtf(P);
        #pragma unroll
        for (int s = 0; s < 8; s++) {
            float e = eps0[((size_t)s * B + b) * 64 + tid];
            zout[(((size_t)s * B + b) * T + 0) * 64 + tid] = m + sq * e;
        }
        float Q0 = softplus_f(log_Q_0[tid]);
        float d = m - m_0[tid];
        term = 0.5f * (logf(Q0) - logf(P) + (P + d * d) / Q0 - 1.f);
    }
    #pragma unroll
    for (int off = 32; off; off >>= 1) term += __shfl_down(term, off);
    if (tid == 0) kl0w[b] = term;
}

// ---------------------------------------------------------------------------
// Kernel C. R14: in-lane phase-A activation (12 tanh on producer lanes,
// direct f16 writes) and in-lane ell (8 exp+fma on producer lanes) —
// deletes stH/stG/stE staging round-trips (2 of 3 LDS round-trips off the
// chain). Phase-B epilogue (heavy softplus/sqrt/log chains) stays DENSE via
// stM/stMU (R5/R9 lesson). Register loss accumulators (R11). Plain
// __syncthreads (R13: lgkm-only barrier neutral).
// ---------------------------------------------------------------------------
__global__ __launch_bounds__(256) void kC(
        const float* __restrict__ Aglob,
        const float* __restrict__ W_le1, const float* __restrict__ W_le2,
        const float* __restrict__ b_le2,
        const float* __restrict__ W_dyn1, const float* __restrict__ b_dyn1,
        const float* __restrict__ W_dyn2, const float* __restrict__ b_dyn2,
        const float* __restrict__ log_Q, const float* __restrict__ eps,
        const float* __restrict__ Cmat, const float* __restrict__ b_c,
        const float* __restrict__ yglob,
        float* __restrict__ zout, float* __restrict__ kcl,
        float* __restrict__ kel) {
    __shared__ alignas(16) _Float16 zSm[16][88];    // rows 0,1 live
    __shared__ alignas(16) _Float16 hidS[16][152];
    __shared__ alignas(16) _Float16 gS[16][88];
    __shared__ alignas(16) float stM[2][136];       // phase-B acc staging
    __shared__ alignas(16) float stMU[2][72];
    __shared__ float bmS[64], bpS[64], bmuS[64], invQS[64];
    __shared__ float redK[4], redL[4];

    const int tid = threadIdx.x;
    const int b = blockIdx.x >> 2, sq = blockIdx.x & 3, s0 = sq * 2;
    const int w = tid >> 6, l = tid & 63;
    const int lo = l & 15, hi = l >> 4;
    const bool prod = (lo < 2);         // producer lanes (valid D cols 0,1)

    // ---- zero f16 LDS (rows >=2 stay zero forever); fill const tables ----
    {
        _Float16* p1 = &zSm[0][0];
        _Float16* p2 = &hidS[0][0];
        _Float16* p3 = &gS[0][0];
        for (int i = tid; i < 16 * 88; i += 256) { p1[i] = (_Float16)0.f; p3[i] = (_Float16)0.f; }
        for (int i = tid; i < 16 * 152; i += 256) p2[i] = (_Float16)0.f;
    }
    if (tid < 64) {
        bmS[tid]   = b_le2[tid];
        bpS[tid]   = b_le2[64 + tid];
        bmuS[tid]  = b_dyn2[tid];
        invQS[tid] = 1.f / softplus_f(log_Q[tid]);
    }

    // ---- static weight fragments ----
    f16x8_t a1[2][2], a2[2][4], a3[2], a4[2], aP[2][2];
    #pragma unroll
    for (int ct = 0; ct < 2; ++ct)
        #pragma unroll
        for (int kt = 0; kt < 2; ++kt) {
            f16x8_t f;
            #pragma unroll
            for (int e = 0; e < 8; ++e)
                f[e] = (_Float16)W_le1[(size_t)(128 + kt * 32 + 8 * hi + e) * 128 + (32 * w + 16 * ct + lo)];
            a1[ct][kt] = f;
        }
    #pragma unroll
    for (int ct = 0; ct < 2; ++ct) {
        const int col = (ct == 0 ? 16 * w : 64 + 16 * w) + lo;
        #pragma unroll
        for (int kt = 0; kt < 4; ++kt) {
            f16x8_t f;
            #pragma unroll
            for (int e = 0; e < 8; ++e)
                f[e] = (_Float16)W_le2[(size_t)(kt * 32 + 8 * hi + e) * 128 + col];
            a2[ct][kt] = f;
        }
    }
    #pragma unroll
    for (int kt = 0; kt < 2; ++kt) {
        f16x8_t f, g;
        #pragma unroll
        for (int e = 0; e < 8; ++e) {
            f[e] = (_Float16)W_dyn1[(size_t)(kt * 32 + 8 * hi + e) * 64 + (16 * w + lo)];
            g[e] = (_Float16)W_dyn2[(size_t)(kt * 32 + 8 * hi + e) * 64 + (16 * w + lo)];
        }
        a3[kt] = f; a4[kt] = g;
    }
    #pragma unroll
    for (int ct = 0; ct < 2; ++ct)
        #pragma unroll
        for (int kt = 0; kt < 2; ++kt) {
            f16x8_t f;
            #pragma unroll
            for (int e = 0; e < 8; ++e)
                f[e] = (_Float16)Cmat[(size_t)(kt * 32 + 8 * hi + e) * 128 + (32 * w + 16 * ct + lo)];
            aP[ct][kt] = f;
        }

    // ---- producer-lane constants (valid when prod) ----
    const int pc0 = 32 * w + 4 * hi;            // proj/hid col base
    const int pc1 = pc0 + 16;
    const int gcp = 16 * w + 4 * hi;            // g col base
    f32x4_t bc0, bc1, bd1v;
    #pragma unroll
    for (int r = 0; r < 4; ++r) {
        bc0[r]  = b_c[pc0 + r];
        bc1[r]  = b_c[pc1 + r];
        bd1v[r] = b_dyn1[gcp + r];
    }

    // ---- dense epilogue mappings (lanes l<32) ----
    const int es = (l >> 4) & 1, ec = 16 * w + (l & 15);
    const float* ep = eps + (((size_t)(s0 + es)) * B + b) * 64 + ec;     // t=1
    float*       zp = zout + ((((size_t)(s0 + es)) * B + b) * T + 1) * 64 + ec;
    // producer-lane global pointers (A and y, f32x4 pairs)
    const float* apt = Aglob + ((size_t)b * T + 1) * 128 + pc0;
    const float* ypt = yglob + ((size_t)b * T + 0) * 128 + pc0;

    // ---- register loss accumulators ----
    float klAcc = 0.f;      // lanes l<32
    float ellAcc = 0.f;     // producer lanes

    __syncthreads();
    // ---- stage z0 (2 samples) ----
    if (tid < 128) {
        int ss = tid >> 6, c6 = tid & 63;
        zSm[ss][c6] = (_Float16)zout[(((size_t)(s0 + ss) * B + b) * T + 0) * 64 + c6];
    }
    __syncthreads();

    // ---- software-pipelined prefetch (producer lanes: A t=1, y t=0) ----
    f32x4_t aN0 = {0,0,0,0}, aN1 = {0,0,0,0}, yN0 = {0,0,0,0}, yN1 = {0,0,0,0};
    float eN = 0.f;
    if (prod) {
        aN0 = *(const f32x4_t*)apt; aN1 = *(const f32x4_t*)(apt + 16);
        yN0 = *(const f32x4_t*)ypt; yN1 = *(const f32x4_t*)(ypt + 16);
    }
    if (l < 32) eN = *ep;

    for (int t = 1; t < T; ++t) {
        const f32x4_t aC0 = aN0, aC1 = aN1, yC0 = yN0, yC1 = yN1;
        const float eC = eN;

        // next-step global prefetch (consumed next iteration)
        if (prod) {
            ypt += 128;
            yN0 = *(const f32x4_t*)ypt; yN1 = *(const f32x4_t*)(ypt + 16);
            if (t < T - 1) {
                apt += 128;
                aN0 = *(const f32x4_t*)apt; aN1 = *(const f32x4_t*)(apt + 16);
            }
        }
        if (l < 32 && t < T - 1) { ep += (size_t)S * B * 64; eN = *ep; }

        // ---- phase A MFMAs: z@W1b ; z@Wd1 ; (proj) z@C ----
        const f16x8_t bz0 = *(const f16x8_t*)&zSm[lo][8 * hi];
        const f16x8_t bz1 = *(const f16x8_t*)&zSm[lo][32 + 8 * hi];

        f32x4_t acc1a = {0.f,0.f,0.f,0.f}, acc1b = {0.f,0.f,0.f,0.f}, acc3 = {0.f,0.f,0.f,0.f};
        acc1a = __builtin_amdgcn_mfma_f32_16x16x32_f16(a1[0][0], bz0, acc1a, 0, 0, 0);
        acc1b = __builtin_amdgcn_mfma_f32_16x16x32_f16(a1[1][0], bz0, acc1b, 0, 0, 0);
        acc3  = __builtin_amdgcn_mfma_f32_16x16x32_f16(a3[0],    bz0, acc3,  0, 0, 0);
        acc1a = __builtin_amdgcn_mfma_f32_16x16x32_f16(a1[0][1], bz1, acc1a, 0, 0, 0);
        acc1b = __builtin_amdgcn_mfma_f32_16x16x32_f16(a1[1][1], bz1, acc1b, 0, 0, 0);
        acc3  = __builtin_amdgcn_mfma_f32_16x16x32_f16(a3[1],    bz1, acc3,  0, 0, 0);
        f32x4_t accE0 = {0.f,0.f,0.f,0.f}, accE1 = {0.f,0.f,0.f,0.f};
        accE0 = __builtin_amdgcn_mfma_f32_16x16x32_f16(aP[0][0], bz0, accE0, 0, 0, 0);
        accE1 = __builtin_amdgcn_mfma_f32_16x16x32_f16(aP[1][0], bz0, accE1, 0, 0, 0);
        accE0 = __builtin_amdgcn_mfma_f32_16x16x32_f16(aP[0][1], bz1, accE0, 0, 0, 0);
        accE1 = __builtin_amdgcn_mfma_f32_16x16x32_f16(aP[1][1], bz1, accE1, 0, 0, 0);

        // ---- IN-LANE activation + ell (producer lanes; 12 tanh + 8 exp) ----
        if (prod) {
            f16x4_t hv0, hv1, gv;
            #pragma unroll
            for (int r = 0; r < 4; ++r) {
                hv0[r] = (_Float16)fast_tanh(acc1a[r] + aC0[r]);
                hv1[r] = (_Float16)fast_tanh(acc1b[r] + aC1[r]);
                gv[r]  = (_Float16)fast_tanh(acc3[r] + bd1v[r]);
            }
            *(f16x4_t*)&hidS[lo][pc0] = hv0;
            *(f16x4_t*)&hidS[lo][pc1] = hv1;
            *(f16x4_t*)&gS[lo][gcp]   = gv;
            float te = 0.f;
            #pragma unroll
            for (int r = 0; r < 4; ++r) {
                float lr0 = accE0[r] + bc0[r];
                float lr1 = accE1[r] + bc1[r];
                te += yC0[r] * lr0 - __expf(lr0);
                te += yC1[r] * lr1 - __expf(lr1);
            }
            ellAcc += 0.125f * te;
            if (sq == 0 && lo == 0) {
                #pragma unroll
                for (int r = 0; r < 4; ++r)
                    ellAcc -= gaOf(yC0[r]) + gaOf(yC1[r]);
            }
        }
        __syncthreads();   // (1) hid/g visible cross-wave

        // ---- phase B MFMAs: hid@W2 ; g@Wd2 ----
        const f16x8_t bh0 = *(const f16x8_t*)&hidS[lo][ 0 + 8 * hi];
        const f16x8_t bh1 = *(const f16x8_t*)&hidS[lo][32 + 8 * hi];
        const f16x8_t bh2 = *(const f16x8_t*)&hidS[lo][64 + 8 * hi];
        const f16x8_t bh3 = *(const f16x8_t*)&hidS[lo][96 + 8 * hi];
        const f16x8_t bg0 = *(const f16x8_t*)&gS[lo][8 * hi];
        const f16x8_t bg1 = *(const f16x8_t*)&gS[lo][32 + 8 * hi];

        f32x4_t accm = {0.f,0.f,0.f,0.f}, accp = {0.f,0.f,0.f,0.f}, acc4 = {0.f,0.f,0.f,0.f};
        accm = __builtin_amdgcn_mfma_f32_16x16x32_f16(a2[0][0], bh0, accm, 0, 0, 0);
        accp = __builtin_amdgcn_mfma_f32_16x16x32_f16(a2[1][0], bh0, accp, 0, 0, 0);
        acc4 = __builtin_amdgcn_mfma_f32_16x16x32_f16(a4[0],    bg0, acc4, 0, 0, 0);
        accm = __builtin_amdgcn_mfma_f32_16x16x32_f16(a2[0][1], bh1, accm, 0, 0, 0);
        accp = __builtin_amdgcn_mfma_f32_16x16x32_f16(a2[1][1], bh1, accp, 0, 0, 0);
        acc4 = __builtin_amdgcn_mfma_f32_16x16x32_f16(a4[1],    bg1, acc4, 0, 0, 0);
        accm = __builtin_amdgcn_mfma_f32_16x16x32_f16(a2[0][2], bh2, accm, 0, 0, 0);
        accp = __builtin_amdgcn_mfma_f32_16x16x32_f16(a2[1][2], bh2, accp, 0, 0, 0);
        accm = __builtin_amdgcn_mfma_f32_16x16x32_f16(a2[0][3], bh3, accm, 0, 0, 0);
        accp = __builtin_amdgcn_mfma_f32_16x16x32_f16(a2[1][3], bh3, accp, 0, 0, 0);

        // ---- phase-B staging (only remaining round-trip) ----
        if (prod) {
            *(f32x4_t*)&stM[lo][16 * w + 4 * hi]       = accm;
            *(f32x4_t*)&stM[lo][64 + 16 * w + 4 * hi]  = accp;
            *(f32x4_t*)&stMU[lo][16 * w + 4 * hi]      = acc4;
        }
        asm volatile("" ::: "memory");

        // ---- dense epilogue + KL ACCUMULATION (lanes l<32) ----
        if (l < 32) {
            float m  = stM[es][ec] + bmS[ec];
            float P  = softplus_fast(stM[es][64 + ec] + bpS[ec]);
            float mu = stMU[es][ec] + bmuS[ec];
            float iq = invQS[ec];
            float z  = m + sqrtf(P) * eC;
            *zp = z; zp += 64;
            zSm[es][ec] = (_Float16)z;
            float d = m - mu;
            klAcc += (P + d * d) * iq - __logf(P * iq) - 1.f;
        }
        __syncthreads();   // (2) zSm visible for next step
    }

    // ---- tail: projection of z_{T-1} (time T-1) into ellAcc ----
    {
        const f16x8_t bz0 = *(const f16x8_t*)&zSm[lo][8 * hi];
        const f16x8_t bz1 = *(const f16x8_t*)&zSm[lo][32 + 8 * hi];
        f32x4_t accE0 = {0.f,0.f,0.f,0.f}, accE1 = {0.f,0.f,0.f,0.f};
        accE0 = __builtin_amdgcn_mfma_f32_16x16x32_f16(aP[0][0], bz0, accE0, 0, 0, 0);
        accE1 = __builtin_amdgcn_mfma_f32_16x16x32_f16(aP[1][0], bz0, accE1, 0, 0, 0);
        accE0 = __builtin_amdgcn_mfma_f32_16x16x32_f16(aP[0][1], bz1, accE0, 0, 0, 0);
        accE1 = __builtin_amdgcn_mfma_f32_16x16x32_f16(aP[1][1], bz1, accE1, 0, 0, 0);
        if (prod) {
            float te = 0.f;
            #pragma unroll
            for (int r = 0; r < 4; ++r) {
                float lr0 = accE0[r] + bc0[r];
                float lr1 = accE1[r] + bc1[r];
                te += yN0[r] * lr0 - __expf(lr0);
                te += yN1[r] * lr1 - __expf(lr1);
            }
            ellAcc += 0.125f * te;
            if (sq == 0 && lo == 0) {
                #pragma unroll
                for (int r = 0; r < 4; ++r)
                    ellAcc -= gaOf(yN0[r]) + gaOf(yN1[r]);
            }
        }
    }

    // ---- ONE reduction for the whole kernel ----
    float kv = klAcc;          // lanes l<32
    kv += __shfl_down(kv, 16);
    kv += __shfl_down(kv, 8);
    kv += __shfl_down(kv, 4);
    kv += __shfl_down(kv, 2);
    kv += __shfl_down(kv, 1);
    float ev = ellAcc;         // producer lanes; full-wave tree sums all
    ev += __shfl_down(ev, 32);
    ev += __shfl_down(ev, 16);
    ev += __shfl_down(ev, 8);
    ev += __shfl_down(ev, 4);
    ev += __shfl_down(ev, 2);
    ev += __shfl_down(ev, 1);
    if (l == 0) { redK[w] = kv; redL[w] = ev; }
    __syncthreads();
    if (tid == 0) {
        kcl[blockIdx.x] = 0.0625f * (redK[0] + redK[1] + redK[2] + redK[3]);
        kel[blockIdx.x] = redL[0] + redL[1] + redL[2] + redL[3];
    }
}

// ---------------------------------------------------------------------------
// Kernel M: m_stat = mean over s of z.
// ---------------------------------------------------------------------------
__global__ __launch_bounds__(256) void kM(
        const float* __restrict__ zin, float* __restrict__ ms) {
    const int idx = blockIdx.x * 256 + threadIdx.x;     // over B*T*16 float4s
    const float4* z4 = (const float4*)zin;
    float4 acc = {0.f, 0.f, 0.f, 0.f};
    #pragma unroll
    for (int s = 0; s < 8; s++) {
        float4 v = z4[(size_t)s * BT * 16 + idx];
        acc.x += v.x; acc.y += v.y; acc.z += v.z; acc.w += v.w;
    }
    acc.x *= 0.125f; acc.y *= 0.125f; acc.z *= 0.125f; acc.w *= 0.125f;
    ((float4*)ms)[idx] = acc;
}

// ---------------------------------------------------------------------------
// Kernel R: loss = ( sum_b kl0[b] + sum_blk kcl - sum_blk kel ) / B
// ---------------------------------------------------------------------------
__global__ __launch_bounds__(256) void kR(
        const float* __restrict__ kl0w, const float* __restrict__ kcl,
        const float* __restrict__ kel, float* __restrict__ out0) {
    __shared__ float red4[4];
    const int tid = threadIdx.x;
    float acc = 0.f;
    #pragma unroll
    for (int ii = 0; ii < 2; ii++) {
        int i = tid + ii * 256;
        acc += kcl[i] - kel[i];
    }
    if (tid < 128) acc += kl0w[tid];
    #pragma unroll
    for (int off = 32; off; off >>= 1) acc += __shfl_down(acc, off);
    if ((tid & 63) == 0) red4[tid >> 6] = acc;
    __syncthreads();
    if (tid == 0) out0[0] = (red4[0] + red4[1] + red4[2] + red4[3]) * (1.0f / B);
}

// ---------------------------------------------------------------------------
extern "C" void kernel_launch(void* const* d_in, const int* in_sizes, int n_in,
                              void* d_out, int out_size, void* d_ws, size_t ws_size,
                              hipStream_t stream) {
    const float* y      = (const float*)d_in[0];
    const float* W_be   = (const float*)d_in[2];
    const float* b_be   = (const float*)d_in[3];
    const float* W_ic   = (const float*)d_in[4];
    const float* b_ic   = (const float*)d_in[5];
    const float* W_le1  = (const float*)d_in[6];
    const float* b_le1  = (const float*)d_in[7];
    const float* W_le2  = (const float*)d_in[8];
    const float* b_le2  = (const float*)d_in[9];
    const float* W_dyn1 = (const float*)d_in[10];
    const float* b_dyn1 = (const float*)d_in[11];
    const float* W_dyn2 = (const float*)d_in[12];
    const float* b_dyn2 = (const float*)d_in[13];
    const float* C      = (const float*)d_in[14];
    const float* b_c    = (const float*)d_in[15];
    const float* log_Q  = (const float*)d_in[16];
    const float* m_0    = (const float*)d_in[17];
    const float* log_Q_0= (const float*)d_in[18];
    const float* eps0   = (const float*)d_in[19];
    const float* eps    = (const float*)d_in[20];

    float* out = (float*)d_out;
    float* zo  = out + 1;
    float* ms  = out + 1 + (size_t)S * B * T * L;

    float* ws   = (float*)d_ws;
    float* kl0w = ws;                                      // B
    float* kcl  = kl0w + B;                                // 512
    float* kel  = kcl + 512;                               // 512
    float* h0   = kel + 512;                               // B*128
    float* A    = h0 + (size_t)B * 128;                    // B*T*128

    kA<<<1024, 256, 0, stream>>>(y, W_be, b_be, W_le1, b_le1, A, h0);
    kB<<<128, 128, 0, stream>>>(h0, W_ic, b_ic, m_0, log_Q_0, eps0, zo, kl0w);
    kC<<<512, 256, 0, stream>>>(A, W_le1, W_le2, b_le2, W_dyn1, b_dyn1,
                                W_dyn2, b_dyn2, log_Q, eps, C, b_c, y,
                                zo, kcl, kel);
    kM<<<2048, 256, 0, stream>>>(zo, ms);
    kR<<<1, 256, 0, stream>>>(kl0w, kcl, kel, out);
}

// Round 15
// 398.181 us; speedup vs baseline: 1.4770x; 1.4770x over previous
//
#include <hip/hip_runtime.h>

// Problem constants
constexpr int S = 8, B = 128, T = 256, N = 128;
constexpr int L = 64, Hh = 128, Hd = 64, Hl = 128;
constexpr int BT = B * T;

#define DEVFN __device__ __forceinline__

typedef float    f32x4_t __attribute__((ext_vector_type(4)));
typedef _Float16 f16x8_t __attribute__((ext_vector_type(8)));
typedef _Float16 f16x4_t __attribute__((ext_vector_type(4)));

DEVFN float softplus_f(float x) {            // accurate (prologue only)
    return (x > 0.f) ? (x + log1pf(expf(-x))) : log1pf(expf(x));
}
DEVFN float softplus_fast(float x) {         // branchless, native trans
    return fmaxf(x, 0.f) + __logf(1.f + __expf(-fabsf(x)));
}
DEVFN float fast_tanh(float x) {
    float ex = __builtin_exp2f(x * 2.885390081777927f);
    return 1.f - 2.f / (ex + 1.f);
}
DEVFN float gaOf(float yv) {                 // gammaln(y+1), y in {0..4}
    int yi = (int)yv;
    return (yi < 2) ? 0.f
         : ((yi == 2) ? 0.6931471805599453f
         : ((yi == 3) ? 1.791759469228055f : 3.1780538303479458f));
}

// ---------------------------------------------------------------------------
// Kernel A (MFMA): per (b,t) row: h = tanh(y@W_be + b_be); A = h@W1a + b_le1.
// ---------------------------------------------------------------------------
__global__ __launch_bounds__(256) void kA(
        const float* __restrict__ y,
        const float* __restrict__ W_be, const float* __restrict__ b_be,
        const float* __restrict__ W_le1, const float* __restrict__ b_le1,
        float* __restrict__ A, float* __restrict__ h0) {
    __shared__ alignas(16) _Float16 yS[32][136];   // [row][n] pad 68 dw
    __shared__ alignas(16) _Float16 hS[32][152];   // pad 76 dw
    __shared__ alignas(16) float    st[32][136];   // f32 acc staging
    __shared__ float bbeS[128];

    const int tid = threadIdx.x;
    const int w = tid >> 6, l = tid & 63;
    const int lo = l & 15, hi = l >> 4;
    const int bt0 = blockIdx.x * 32;

    if (tid < 128) bbeS[tid] = b_be[tid];

    // ---- load y rows -> f16 LDS ----
    {
        const float4* y4 = (const float4*)(y + (size_t)bt0 * 128);
        #pragma unroll
        for (int k = 0; k < 4; ++k) {
            int i = k * 256 + tid;              // 1024 float4s
            float4 v = y4[i];
            int row = i >> 5, c4 = (i & 31) * 4;
            f16x4_t h4;
            h4[0] = (_Float16)v.x; h4[1] = (_Float16)v.y;
            h4[2] = (_Float16)v.z; h4[3] = (_Float16)v.w;
            *(f16x4_t*)&yS[row][c4] = h4;
        }
    }

    // ---- weight fragments (64 VGPRs) ----
    f16x8_t awb[2][4], awa[2][4];
    #pragma unroll
    for (int ct = 0; ct < 2; ++ct)
        #pragma unroll
        for (int kt = 0; kt < 4; ++kt) {
            f16x8_t f, g;
            #pragma unroll
            for (int e = 0; e < 8; ++e) {
                size_t off = (size_t)(kt * 32 + 8 * hi + e) * 128 + (32 * w + 16 * ct + lo);
                f[e] = (_Float16)W_be[off];
                g[e] = (_Float16)W_le1[off];    // rows 0..127 = W1a
            }
            awb[ct][kt] = f; awa[ct][kt] = g;
        }
    const f32x4_t bl0 = *(const f32x4_t*)&b_le1[32 * w + 4 * hi];
    const f32x4_t bl1 = *(const f32x4_t*)&b_le1[32 * w + 16 + 4 * hi];
    __syncthreads();

    // ---- GEMM1: h_pre = y @ W_be ----
    #pragma unroll
    for (int rt = 0; rt < 2; ++rt) {
        f32x4_t acc0 = {0.f,0.f,0.f,0.f}, acc1 = {0.f,0.f,0.f,0.f};
        #pragma unroll
        for (int kt = 0; kt < 4; ++kt) {
            const f16x8_t bf = *(const f16x8_t*)&yS[16 * rt + lo][kt * 32 + 8 * hi];
            acc0 = __builtin_amdgcn_mfma_f32_16x16x32_f16(awb[0][kt], bf, acc0, 0, 0, 0);
            acc1 = __builtin_amdgcn_mfma_f32_16x16x32_f16(awb[1][kt], bf, acc1, 0, 0, 0);
        }
        *(f32x4_t*)&st[16 * rt + lo][32 * w + 4 * hi]      = acc0;
        *(f32x4_t*)&st[16 * rt + lo][32 * w + 16 + 4 * hi] = acc1;
    }
    __syncthreads();

    // ---- dense tanh pass: 16 values/thread ----
    {
        const int trow = tid >> 3, cb = (tid & 7) * 16;
        const bool isH0 = ((bt0 & 255) == 0) && (trow == 0);
        float* h0p = h0 + (size_t)(bt0 >> 8) * 128;
        #pragma unroll
        for (int j = 0; j < 16; ++j) {
            float hv = fast_tanh(st[trow][cb + j] + bbeS[cb + j]);
            hS[trow][cb + j] = (_Float16)hv;
            if (isH0) h0p[cb + j] = hv;
        }
    }
    __syncthreads();

    // ---- GEMM2: A = h @ W1a + b_le1 ----
    #pragma unroll
    for (int rt = 0; rt < 2; ++rt) {
        f32x4_t acc0 = {0.f,0.f,0.f,0.f}, acc1 = {0.f,0.f,0.f,0.f};
        #pragma unroll
        for (int kt = 0; kt < 4; ++kt) {
            const f16x8_t bf = *(const f16x8_t*)&hS[16 * rt + lo][kt * 32 + 8 * hi];
            acc0 = __builtin_amdgcn_mfma_f32_16x16x32_f16(awa[0][kt], bf, acc0, 0, 0, 0);
            acc1 = __builtin_amdgcn_mfma_f32_16x16x32_f16(awa[1][kt], bf, acc1, 0, 0, 0);
        }
        acc0 += bl0; acc1 += bl1;
        float* Ar = A + (size_t)(bt0 + 16 * rt + lo) * 128;
        *(f32x4_t*)&Ar[32 * w + 4 * hi]      = acc0;
        *(f32x4_t*)&Ar[32 * w + 16 + 4 * hi] = acc1;
    }
}

// ---------------------------------------------------------------------------
// Kernel B: initial step (t=0). Writes kl0[b] scalar.
// ---------------------------------------------------------------------------
__global__ __launch_bounds__(128) void kB(
        const float* __restrict__ h0, const float* __restrict__ W_ic,
        const float* __restrict__ b_ic, const float* __restrict__ m_0,
        const float* __restrict__ log_Q_0, const float* __restrict__ eps0,
        float* __restrict__ zout, float* __restrict__ kl0w) {
    __shared__ float hr[128];
    __shared__ float mp[128];
    const int b = blockIdx.x, tid = threadIdx.x;
    hr[tid] = h0[b * 128 + tid];
    __syncthreads();
    float acc = b_ic[tid];
    #pragma unroll 8
    for (int k = 0; k < 128; k++) acc += hr[k] * W_ic[k * 128 + tid];
    mp[tid] = acc;
    __syncthreads();

    float term = 0.f;
    if (tid < 64) {
        float m = mp[tid];
        float P = softplus_f(mp[tid + 64]);
        float sq = sqrtf(P);
        #pragma unroll
        for (int s = 0; s < 8; s++) {
            float e = eps0[((size_t)s * B + b) * 64 + tid];
            zout[(((size_t)s * B + b) * T + 0) * 64 + tid] = m + sq * e;
        }
        float Q0 = softplus_f(log_Q_0[tid]);
        float d = m - m_0[tid];
        term = 0.5f * (logf(Q0) - logf(P) + (P + d * d) / Q0 - 1.f);
    }
    #pragma unroll
    for (int off = 32; off; off >>= 1) term += __shfl_down(term, off);
    if (tid == 0) kl0w[b] = term;
}

// ---------------------------------------------------------------------------
// Kernel C (R15 = R12 base + s_setprio around MFMA clusters + deferred KL
// trans-ops). 512 blocks = (b, sq -> 2 samples); 4 waves.
// Structure lessons baked in: NS=2; DENSE activation/epilogue via
// wave-private f32 staging (in-lane masked = 1.5-2x worse, R5/R9/R14);
// register loss accumulators (R11: -10 ds_bpermute/step = -40%);
// plain __syncthreads (R10/R13: vmcnt-drain theory falsified twice).
// setprio: T5 evidence — helps when independent blocks/CU sit at different
// phases (attn +4-7%); our 2 blocks/CU drift freely.
// Deferred KL: stash P, d^2 in regs at epilogue; the 2 __logf chains move
// past barrier(2), overlapping next step's phase-A MFMAs.
// ---------------------------------------------------------------------------
__global__ __launch_bounds__(256) void kC(
        const float* __restrict__ Aglob,
        const float* __restrict__ W_le1, const float* __restrict__ W_le2,
        const float* __restrict__ b_le2,
        const float* __restrict__ W_dyn1, const float* __restrict__ b_dyn1,
        const float* __restrict__ W_dyn2, const float* __restrict__ b_dyn2,
        const float* __restrict__ log_Q, const float* __restrict__ eps,
        const float* __restrict__ Cmat, const float* __restrict__ b_c,
        const float* __restrict__ yglob,
        float* __restrict__ zout, float* __restrict__ kcl,
        float* __restrict__ kel) {
    __shared__ alignas(16) _Float16 zSm[16][88];    // rows 0,1 live
    __shared__ alignas(16) _Float16 hidS[16][152];
    __shared__ alignas(16) _Float16 gS[16][88];
    __shared__ alignas(16) float stH[2][136];       // phase-A acc staging
    __shared__ alignas(16) float stG[2][72];
    __shared__ alignas(16) float stM[2][136];       // phase-B acc staging
    __shared__ alignas(16) float stMU[2][72];
    __shared__ alignas(16) float stE[2][136];       // projection staging
    __shared__ float bmS[64], bpS[64], bmuS[64], bd1S[64], invQS[64];
    __shared__ float bcS[128];
    __shared__ float redK[4], redL[4];

    const int tid = threadIdx.x;
    const int b = blockIdx.x >> 2, sq = blockIdx.x & 3, s0 = sq * 2;
    const int w = tid >> 6, l = tid & 63;
    const int lo = l & 15, hi = l >> 4;
    const bool prod = (lo < 2);         // producer lanes (valid D cols 0,1)

    // ---- zero f16 LDS (rows >=2 stay zero forever); fill const tables ----
    {
        _Float16* p1 = &zSm[0][0];
        _Float16* p2 = &hidS[0][0];
        _Float16* p3 = &gS[0][0];
        for (int i = tid; i < 16 * 88; i += 256) { p1[i] = (_Float16)0.f; p3[i] = (_Float16)0.f; }
        for (int i = tid; i < 16 * 152; i += 256) p2[i] = (_Float16)0.f;
    }
    if (tid < 64) {
        bmS[tid]   = b_le2[tid];
        bpS[tid]   = b_le2[64 + tid];
        bmuS[tid]  = b_dyn2[tid];
        bd1S[tid]  = b_dyn1[tid];
        invQS[tid] = 1.f / softplus_f(log_Q[tid]);
    }
    if (tid < 128) bcS[tid] = b_c[tid];

    // ---- static weight fragments ----
    f16x8_t a1[2][2], a2[2][4], a3[2], a4[2], aP[2][2];
    #pragma unroll
    for (int ct = 0; ct < 2; ++ct)
        #pragma unroll
        for (int kt = 0; kt < 2; ++kt) {
            f16x8_t f;
            #pragma unroll
            for (int e = 0; e < 8; ++e)
                f[e] = (_Float16)W_le1[(size_t)(128 + kt * 32 + 8 * hi + e) * 128 + (32 * w + 16 * ct + lo)];
            a1[ct][kt] = f;
        }
    #pragma unroll
    for (int ct = 0; ct < 2; ++ct) {
        const int col = (ct == 0 ? 16 * w : 64 + 16 * w) + lo;
        #pragma unroll
        for (int kt = 0; kt < 4; ++kt) {
            f16x8_t f;
            #pragma unroll
            for (int e = 0; e < 8; ++e)
                f[e] = (_Float16)W_le2[(size_t)(kt * 32 + 8 * hi + e) * 128 + col];
            a2[ct][kt] = f;
        }
    }
    #pragma unroll
    for (int kt = 0; kt < 2; ++kt) {
        f16x8_t f, g;
        #pragma unroll
        for (int e = 0; e < 8; ++e) {
            f[e] = (_Float16)W_dyn1[(size_t)(kt * 32 + 8 * hi + e) * 64 + (16 * w + lo)];
            g[e] = (_Float16)W_dyn2[(size_t)(kt * 32 + 8 * hi + e) * 64 + (16 * w + lo)];
        }
        a3[kt] = f; a4[kt] = g;
    }
    #pragma unroll
    for (int ct = 0; ct < 2; ++ct)
        #pragma unroll
        for (int kt = 0; kt < 2; ++kt) {
            f16x8_t f;
            #pragma unroll
            for (int e = 0; e < 8; ++e)
                f[e] = (_Float16)Cmat[(size_t)(kt * 32 + 8 * hi + e) * 128 + (32 * w + 16 * ct + lo)];
            aP[ct][kt] = f;
        }

    // ---- dense wave-local role mappings ----
    const int ha = l >> 5, hc = 32 * w + (l & 31);  // activation/proj: sample,col
    const int ga2 = (l >> 4) & 1, gc = 16 * w + (l & 15);
    const int es = ga2, ec = gc;                    // epilogue: sample,col
    const float* ap = Aglob + ((size_t)b * T + 1) * 128 + hc;
    const float* yp = yglob + ((size_t)b * T + 0) * 128 + hc;
    const float* ep = eps + (((size_t)(s0 + es)) * B + b) * 64 + ec;     // t=1
    float*       zp = zout + ((((size_t)(s0 + es)) * B + b) * T + 1) * 64 + ec;

    // ---- register loss accumulators ----
    float klAcc = 0.f;      // lanes l<32
    float ellAcc = 0.f;     // all lanes
    float kP_pend = 1.f, kDD_pend = 0.f, kIQ_pend = 0.f;  // deferred KL pieces

    __syncthreads();
    // ---- stage z0 (2 samples) ----
    if (tid < 128) {
        int ss = tid >> 6, c6 = tid & 63;
        zSm[ss][c6] = (_Float16)zout[(((size_t)(s0 + ss) * B + b) * T + 0) * 64 + c6];
    }
    __syncthreads();

    // ---- software-pipelined prefetch (t=1; y row for proj time 0) ----
    float aN = *ap;
    float yN = *yp;
    float eN = 0.f;
    if (l < 32) eN = *ep;

    for (int t = 1; t < T; ++t) {
        const float aC = aN, eC = eN, yC = yN;

        // deferred KL from previous step (overlaps phase-A MFMAs below)
        if (t > 1 && l < 32)
            klAcc += (kP_pend + kDD_pend) * kIQ_pend
                   - __logf(kP_pend * kIQ_pend) - 1.f;

        // next-step global prefetch (consumed next iteration)
        yp += 128; yN = *yp;                       // y[b][t] (proj time t)
        if (t < T - 1) {
            ap += 128; aN = *ap;
            if (l < 32) { ep += (size_t)S * B * 64; eN = *ep; }
        }

        // ---- phase A MFMAs: z@W1b ; z@Wd1 ; (proj) z@C ----
        const f16x8_t bz0 = *(const f16x8_t*)&zSm[lo][8 * hi];
        const f16x8_t bz1 = *(const f16x8_t*)&zSm[lo][32 + 8 * hi];

        __builtin_amdgcn_s_setprio(1);
        f32x4_t acc1a = {0.f,0.f,0.f,0.f}, acc1b = {0.f,0.f,0.f,0.f}, acc3 = {0.f,0.f,0.f,0.f};
        acc1a = __builtin_amdgcn_mfma_f32_16x16x32_f16(a1[0][0], bz0, acc1a, 0, 0, 0);
        acc1b = __builtin_amdgcn_mfma_f32_16x16x32_f16(a1[1][0], bz0, acc1b, 0, 0, 0);
        acc3  = __builtin_amdgcn_mfma_f32_16x16x32_f16(a3[0],    bz0, acc3,  0, 0, 0);
        acc1a = __builtin_amdgcn_mfma_f32_16x16x32_f16(a1[0][1], bz1, acc1a, 0, 0, 0);
        acc1b = __builtin_amdgcn_mfma_f32_16x16x32_f16(a1[1][1], bz1, acc1b, 0, 0, 0);
        acc3  = __builtin_amdgcn_mfma_f32_16x16x32_f16(a3[1],    bz1, acc3,  0, 0, 0);
        // projection of z_{t-1} (off the recurrence chain)
        f32x4_t accE0 = {0.f,0.f,0.f,0.f}, accE1 = {0.f,0.f,0.f,0.f};
        accE0 = __builtin_amdgcn_mfma_f32_16x16x32_f16(aP[0][0], bz0, accE0, 0, 0, 0);
        accE1 = __builtin_amdgcn_mfma_f32_16x16x32_f16(aP[1][0], bz0, accE1, 0, 0, 0);
        accE0 = __builtin_amdgcn_mfma_f32_16x16x32_f16(aP[0][1], bz1, accE0, 0, 0, 0);
        accE1 = __builtin_amdgcn_mfma_f32_16x16x32_f16(aP[1][1], bz1, accE1, 0, 0, 0);
        __builtin_amdgcn_s_setprio(0);

        // wave-private staging (same-wave LDS ordering; no barrier)
        if (prod) {
            *(f32x4_t*)&stH[lo][32 * w + 4 * hi]      = acc1a;
            *(f32x4_t*)&stH[lo][32 * w + 16 + 4 * hi] = acc1b;
            *(f32x4_t*)&stG[lo][16 * w + 4 * hi]      = acc3;
        }
        asm volatile("" ::: "memory");

        // ---- dense activation (same wave consumes its own strip) ----
        hidS[ha][hc] = (_Float16)fast_tanh(stH[ha][hc] + aC);
        if (l < 32)
            gS[ga2][gc] = (_Float16)fast_tanh(stG[ga2][gc] + bd1S[gc]);
        __syncthreads();   // (1) hid/g visible cross-wave

        // ---- phase B MFMAs: hid@W2 ; g@Wd2 ----
        const f16x8_t bh0 = *(const f16x8_t*)&hidS[lo][ 0 + 8 * hi];
        const f16x8_t bh1 = *(const f16x8_t*)&hidS[lo][32 + 8 * hi];
        const f16x8_t bh2 = *(const f16x8_t*)&hidS[lo][64 + 8 * hi];
        const f16x8_t bh3 = *(const f16x8_t*)&hidS[lo][96 + 8 * hi];
        const f16x8_t bg0 = *(const f16x8_t*)&gS[lo][8 * hi];
        const f16x8_t bg1 = *(const f16x8_t*)&gS[lo][32 + 8 * hi];

        __builtin_amdgcn_s_setprio(1);
        f32x4_t accm = {0.f,0.f,0.f,0.f}, accp = {0.f,0.f,0.f,0.f}, acc4 = {0.f,0.f,0.f,0.f};
        accm = __builtin_amdgcn_mfma_f32_16x16x32_f16(a2[0][0], bh0, accm, 0, 0, 0);
        accp = __builtin_amdgcn_mfma_f32_16x16x32_f16(a2[1][0], bh0, accp, 0, 0, 0);
        acc4 = __builtin_amdgcn_mfma_f32_16x16x32_f16(a4[0],    bg0, acc4, 0, 0, 0);
        accm = __builtin_amdgcn_mfma_f32_16x16x32_f16(a2[0][1], bh1, accm, 0, 0, 0);
        accp = __builtin_amdgcn_mfma_f32_16x16x32_f16(a2[1][1], bh1, accp, 0, 0, 0);
        acc4 = __builtin_amdgcn_mfma_f32_16x16x32_f16(a4[1],    bg1, acc4, 0, 0, 0);
        accm = __builtin_amdgcn_mfma_f32_16x16x32_f16(a2[0][2], bh2, accm, 0, 0, 0);
        accp = __builtin_amdgcn_mfma_f32_16x16x32_f16(a2[1][2], bh2, accp, 0, 0, 0);
        accm = __builtin_amdgcn_mfma_f32_16x16x32_f16(a2[0][3], bh3, accm, 0, 0, 0);
        accp = __builtin_amdgcn_mfma_f32_16x16x32_f16(a2[1][3], bh3, accp, 0, 0, 0);
        __builtin_amdgcn_s_setprio(0);

        // ---- projection staging + dense ell ACCUMULATION ----
        if (prod) {
            *(f32x4_t*)&stE[lo][32 * w + 4 * hi]      = accE0;
            *(f32x4_t*)&stE[lo][32 * w + 16 + 4 * hi] = accE1;
        }
        asm volatile("" ::: "memory");
        {
            float lr = stE[ha][hc] + bcS[hc];
            ellAcc += 0.125f * (yC * lr - __expf(lr));
            if (sq == 0 && ha == 0) ellAcc -= gaOf(yC);
        }

        if (prod) {
            *(f32x4_t*)&stM[lo][16 * w + 4 * hi]       = accm;
            *(f32x4_t*)&stM[lo][64 + 16 * w + 4 * hi]  = accp;
            *(f32x4_t*)&stMU[lo][16 * w + 4 * hi]      = acc4;
        }
        asm volatile("" ::: "memory");

        // ---- dense epilogue (lanes l<32); KL trans-ops DEFERRED ----
        if (l < 32) {
            float m  = stM[es][ec] + bmS[ec];
            float P  = softplus_fast(stM[es][64 + ec] + bpS[ec]);
            float mu = stMU[es][ec] + bmuS[ec];
            float z  = m + sqrtf(P) * eC;
            *zp = z; zp += 64;
            zSm[es][ec] = (_Float16)z;
            float d = m - mu;
            kP_pend = P; kDD_pend = d * d; kIQ_pend = invQS[ec];
        }
        __syncthreads();   // (2) zSm visible for next step
    }
    // flush last step's deferred KL
    if (l < 32)
        klAcc += (kP_pend + kDD_pend) * kIQ_pend
               - __logf(kP_pend * kIQ_pend) - 1.f;

    // ---- tail: projection of z_{T-1} (time T-1) into ellAcc ----
    {
        const f16x8_t bz0 = *(const f16x8_t*)&zSm[lo][8 * hi];
        const f16x8_t bz1 = *(const f16x8_t*)&zSm[lo][32 + 8 * hi];
        f32x4_t accE0 = {0.f,0.f,0.f,0.f}, accE1 = {0.f,0.f,0.f,0.f};
        accE0 = __builtin_amdgcn_mfma_f32_16x16x32_f16(aP[0][0], bz0, accE0, 0, 0, 0);
        accE1 = __builtin_amdgcn_mfma_f32_16x16x32_f16(aP[1][0], bz0, accE1, 0, 0, 0);
        accE0 = __builtin_amdgcn_mfma_f32_16x16x32_f16(aP[0][1], bz1, accE0, 0, 0, 0);
        accE1 = __builtin_amdgcn_mfma_f32_16x16x32_f16(aP[1][1], bz1, accE1, 0, 0, 0);
        if (prod) {
            *(f32x4_t*)&stE[lo][32 * w + 4 * hi]      = accE0;
            *(f32x4_t*)&stE[lo][32 * w + 16 + 4 * hi] = accE1;
        }
        asm volatile("" ::: "memory");
        float lr = stE[ha][hc] + bcS[hc];
        ellAcc += 0.125f * (yN * lr - __expf(lr));
        if (sq == 0 && ha == 0) ellAcc -= gaOf(yN);
    }

    // ---- ONE reduction for the whole kernel ----
    float kv = klAcc;          // lanes l<32
    kv += __shfl_down(kv, 16);
    kv += __shfl_down(kv, 8);
    kv += __shfl_down(kv, 4);
    kv += __shfl_down(kv, 2);
    kv += __shfl_down(kv, 1);
    float ev = ellAcc;         // all 64 lanes
    ev += __shfl_down(ev, 32);
    ev += __shfl_down(ev, 16);
    ev += __shfl_down(ev, 8);
    ev += __shfl_down(ev, 4);
    ev += __shfl_down(ev, 2);
    ev += __shfl_down(ev, 1);
    if (l == 0) { redK[w] = kv; redL[w] = ev; }
    __syncthreads();
    if (tid == 0) {
        kcl[blockIdx.x] = 0.0625f * (redK[0] + redK[1] + redK[2] + redK[3]);
        kel[blockIdx.x] = redL[0] + redL[1] + redL[2] + redL[3];
    }
}

// ---------------------------------------------------------------------------
// Kernel M: m_stat = mean over s of z.
// ---------------------------------------------------------------------------
__global__ __launch_bounds__(256) void kM(
        const float* __restrict__ zin, float* __restrict__ ms) {
    const int idx = blockIdx.x * 256 + threadIdx.x;     // over B*T*16 float4s
    const float4* z4 = (const float4*)zin;
    float4 acc = {0.f, 0.f, 0.f, 0.f};
    #pragma unroll
    for (int s = 0; s < 8; s++) {
        float4 v = z4[(size_t)s * BT * 16 + idx];
        acc.x += v.x; acc.y += v.y; acc.z += v.z; acc.w += v.w;
    }
    acc.x *= 0.125f; acc.y *= 0.125f; acc.z *= 0.125f; acc.w *= 0.125f;
    ((float4*)ms)[idx] = acc;
}

// ---------------------------------------------------------------------------
// Kernel R: loss = ( sum_b kl0[b] + sum_blk kcl - sum_blk kel ) / B
// ---------------------------------------------------------------------------
__global__ __launch_bounds__(256) void kR(
        const float* __restrict__ kl0w, const float* __restrict__ kcl,
        const float* __restrict__ kel, float* __restrict__ out0) {
    __shared__ float red4[4];
    const int tid = threadIdx.x;
    float acc = 0.f;
    #pragma unroll
    for (int ii = 0; ii < 2; ii++) {
        int i = tid + ii * 256;
        acc += kcl[i] - kel[i];
    }
    if (tid < 128) acc += kl0w[tid];
    #pragma unroll
    for (int off = 32; off; off >>= 1) acc += __shfl_down(acc, off);
    if ((tid & 63) == 0) red4[tid >> 6] = acc;
    __syncthreads();
    if (tid == 0) out0[0] = (red4[0] + red4[1] + red4[2] + red4[3]) * (1.0f / B);
}

// ---------------------------------------------------------------------------
extern "C" void kernel_launch(void* const* d_in, const int* in_sizes, int n_in,
                              void* d_out, int out_size, void* d_ws, size_t ws_size,
                              hipStream_t stream) {
    const float* y      = (const float*)d_in[0];
    const float* W_be   = (const float*)d_in[2];
    const float* b_be   = (const float*)d_in[3];
    const float* W_ic   = (const float*)d_in[4];
    const float* b_ic   = (const float*)d_in[5];
    const float* W_le1  = (const float*)d_in[6];
    const float* b_le1  = (const float*)d_in[7];
    const float* W_le2  = (const float*)d_in[8];
    const float* b_le2  = (const float*)d_in[9];
    const float* W_dyn1 = (const float*)d_in[10];
    const float* b_dyn1 = (const float*)d_in[11];
    const float* W_dyn2 = (const float*)d_in[12];
    const float* b_dyn2 = (const float*)d_in[13];
    const float* C      = (const float*)d_in[14];
    const float* b_c    = (const float*)d_in[15];
    const float* log_Q  = (const float*)d_in[16];
    const float* m_0    = (const float*)d_in[17];
    const float* log_Q_0= (const float*)d_in[18];
    const float* eps0   = (const float*)d_in[19];
    const float* eps    = (const float*)d_in[20];

    float* out = (float*)d_out;
    float* zo  = out + 1;
    float* ms  = out + 1 + (size_t)S * B * T * L;

    float* ws   = (float*)d_ws;
    float* kl0w = ws;                                      // B
    float* kcl  = kl0w + B;                                // 512
    float* kel  = kcl + 512;                               // 512
    float* h0   = kel + 512;                               // B*128
    float* A    = h0 + (size_t)B * 128;                    // B*T*128

    kA<<<1024, 256, 0, stream>>>(y, W_be, b_be, W_le1, b_le1, A, h0);
    kB<<<128, 128, 0, stream>>>(h0, W_ic, b_ic, m_0, log_Q_0, eps0, zo, kl0w);
    kC<<<512, 256, 0, stream>>>(A, W_le1, W_le2, b_le2, W_dyn1, b_dyn1,
                                W_dyn2, b_dyn2, log_Q, eps, C, b_c, y,
                                zo, kcl, kel);
    kM<<<2048, 256, 0, stream>>>(zo, ms);
    kR<<<1, 256, 0, stream>>>(kl0w, kcl, kel, out);
}

// Round 16
// 343.636 us; speedup vs baseline: 1.7115x; 1.1587x over previous
//
#include <hip/hip_runtime.h>

// Problem constants
constexpr int S = 8, B = 128, T = 256, N = 128;
constexpr int L = 64, Hh = 128, Hd = 64, Hl = 128;
constexpr int BT = B * T;

#define DEVFN __device__ __forceinline__

typedef float    f32x4_t __attribute__((ext_vector_type(4)));
typedef _Float16 f16x8_t __attribute__((ext_vector_type(8)));
typedef _Float16 f16x4_t __attribute__((ext_vector_type(4)));

DEVFN float softplus_f(float x) {            // accurate (prologue only)
    return (x > 0.f) ? (x + log1pf(expf(-x))) : log1pf(expf(x));
}
DEVFN float softplus_fast(float x) {         // branchless, native trans
    return fmaxf(x, 0.f) + __logf(1.f + __expf(-fabsf(x)));
}
DEVFN float fast_tanh(float x) {
    float ex = __builtin_exp2f(x * 2.885390081777927f);
    return 1.f - 2.f / (ex + 1.f);
}
DEVFN float gaOf(float yv) {                 // gammaln(y+1), y in {0..4}
    int yi = (int)yv;
    return (yi < 2) ? 0.f
         : ((yi == 2) ? 0.6931471805599453f
         : ((yi == 3) ? 1.791759469228055f : 3.1780538303479458f));
}

// ---------------------------------------------------------------------------
// Kernel A (MFMA): per (b,t) row: h = tanh(y@W_be + b_be); A = h@W1a + b_le1.
// ---------------------------------------------------------------------------
__global__ __launch_bounds__(256) void kA(
        const float* __restrict__ y,
        const float* __restrict__ W_be, const float* __restrict__ b_be,
        const float* __restrict__ W_le1, const float* __restrict__ b_le1,
        float* __restrict__ A, float* __restrict__ h0) {
    __shared__ alignas(16) _Float16 yS[32][136];   // [row][n] pad 68 dw
    __shared__ alignas(16) _Float16 hS[32][152];   // pad 76 dw
    __shared__ alignas(16) float    st[32][136];   // f32 acc staging
    __shared__ float bbeS[128];

    const int tid = threadIdx.x;
    const int w = tid >> 6, l = tid & 63;
    const int lo = l & 15, hi = l >> 4;
    const int bt0 = blockIdx.x * 32;

    if (tid < 128) bbeS[tid] = b_be[tid];

    // ---- load y rows -> f16 LDS ----
    {
        const float4* y4 = (const float4*)(y + (size_t)bt0 * 128);
        #pragma unroll
        for (int k = 0; k < 4; ++k) {
            int i = k * 256 + tid;              // 1024 float4s
            float4 v = y4[i];
            int row = i >> 5, c4 = (i & 31) * 4;
            f16x4_t h4;
            h4[0] = (_Float16)v.x; h4[1] = (_Float16)v.y;
            h4[2] = (_Float16)v.z; h4[3] = (_Float16)v.w;
            *(f16x4_t*)&yS[row][c4] = h4;
        }
    }

    // ---- weight fragments (64 VGPRs) ----
    f16x8_t awb[2][4], awa[2][4];
    #pragma unroll
    for (int ct = 0; ct < 2; ++ct)
        #pragma unroll
        for (int kt = 0; kt < 4; ++kt) {
            f16x8_t f, g;
            #pragma unroll
            for (int e = 0; e < 8; ++e) {
                size_t off = (size_t)(kt * 32 + 8 * hi + e) * 128 + (32 * w + 16 * ct + lo);
                f[e] = (_Float16)W_be[off];
                g[e] = (_Float16)W_le1[off];    // rows 0..127 = W1a
            }
            awb[ct][kt] = f; awa[ct][kt] = g;
        }
    const f32x4_t bl0 = *(const f32x4_t*)&b_le1[32 * w + 4 * hi];
    const f32x4_t bl1 = *(const f32x4_t*)&b_le1[32 * w + 16 + 4 * hi];
    __syncthreads();

    // ---- GEMM1: h_pre = y @ W_be ----
    #pragma unroll
    for (int rt = 0; rt < 2; ++rt) {
        f32x4_t acc0 = {0.f,0.f,0.f,0.f}, acc1 = {0.f,0.f,0.f,0.f};
        #pragma unroll
        for (int kt = 0; kt < 4; ++kt) {
            const f16x8_t bf = *(const f16x8_t*)&yS[16 * rt + lo][kt * 32 + 8 * hi];
            acc0 = __builtin_amdgcn_mfma_f32_16x16x32_f16(awb[0][kt], bf, acc0, 0, 0, 0);
            acc1 = __builtin_amdgcn_mfma_f32_16x16x32_f16(awb[1][kt], bf, acc1, 0, 0, 0);
        }
        *(f32x4_t*)&st[16 * rt + lo][32 * w + 4 * hi]      = acc0;
        *(f32x4_t*)&st[16 * rt + lo][32 * w + 16 + 4 * hi] = acc1;
    }
    __syncthreads();

    // ---- dense tanh pass: 16 values/thread ----
    {
        const int trow = tid >> 3, cb = (tid & 7) * 16;
        const bool isH0 = ((bt0 & 255) == 0) && (trow == 0);
        float* h0p = h0 + (size_t)(bt0 >> 8) * 128;
        #pragma unroll
        for (int j = 0; j < 16; ++j) {
            float hv = fast_tanh(st[trow][cb + j] + bbeS[cb + j]);
            hS[trow][cb + j] = (_Float16)hv;
            if (isH0) h0p[cb + j] = hv;
        }
    }
    __syncthreads();

    // ---- GEMM2: A = h @ W1a + b_le1 ----
    #pragma unroll
    for (int rt = 0; rt < 2; ++rt) {
        f32x4_t acc0 = {0.f,0.f,0.f,0.f}, acc1 = {0.f,0.f,0.f,0.f};
        #pragma unroll
        for (int kt = 0; kt < 4; ++kt) {
            const f16x8_t bf = *(const f16x8_t*)&hS[16 * rt + lo][kt * 32 + 8 * hi];
            acc0 = __builtin_amdgcn_mfma_f32_16x16x32_f16(awa[0][kt], bf, acc0, 0, 0, 0);
            acc1 = __builtin_amdgcn_mfma_f32_16x16x32_f16(awa[1][kt], bf, acc1, 0, 0, 0);
        }
        acc0 += bl0; acc1 += bl1;
        float* Ar = A + (size_t)(bt0 + 16 * rt + lo) * 128;
        *(f32x4_t*)&Ar[32 * w + 4 * hi]      = acc0;
        *(f32x4_t*)&Ar[32 * w + 16 + 4 * hi] = acc1;
    }
}

// ---------------------------------------------------------------------------
// Kernel B: initial step (t=0). Writes kl0[b] scalar.
// ---------------------------------------------------------------------------
__global__ __launch_bounds__(128) void kB(
        const float* __restrict__ h0, const float* __restrict__ W_ic,
        const float* __restrict__ b_ic, const float* __restrict__ m_0,
        const float* __restrict__ log_Q_0, const float* __restrict__ eps0,
        float* __restrict__ zout, float* __restrict__ kl0w) {
    __shared__ float hr[128];
    __shared__ float mp[128];
    const int b = blockIdx.x, tid = threadIdx.x;
    hr[tid] = h0[b * 128 + tid];
    __syncthreads();
    float acc = b_ic[tid];
    #pragma unroll 8
    for (int k = 0; k < 128; k++) acc += hr[k] * W_ic[k * 128 + tid];
    mp[tid] = acc;
    __syncthreads();

    float term = 0.f;
    if (tid < 64) {
        float m = mp[tid];
        float P = softplus_f(mp[tid + 64]);
        float sq = sqrtf(P);
        #pragma unroll
        for (int s = 0; s < 8; s++) {
            float e = eps0[((size_t)s * B + b) * 64 + tid];
            zout[(((size_t)s * B + b) * T + 0) * 64 + tid] = m + sq * e;
        }
        float Q0 = softplus_f(log_Q_0[tid]);
        float d = m - m_0[tid];
        term = 0.5f * (logf(Q0) - logf(P) + (P + d * d) / Q0 - 1.f);
    }
    #pragma unroll
    for (int off = 32; off; off >>= 1) term += __shfl_down(term, off);
    if (tid == 0) kl0w[b] = term;
}

// ---------------------------------------------------------------------------
// Kernel C (R16 = R12 minus projection/ell fusion). 512 blocks = (b, sq).
// R8's own data: fusing proj cost kC +117us (serialized 4 MFMAs + stE
// round-trip + exp epilogue into the chain). Projection moves to kP2
// (lean MFMA throughput kernel). kC keeps: NS=2, dense staging epilogues,
// register KL accumulator, plain __syncthreads.
// ---------------------------------------------------------------------------
__global__ __launch_bounds__(256) void kC(
        const float* __restrict__ Aglob,
        const float* __restrict__ W_le1, const float* __restrict__ W_le2,
        const float* __restrict__ b_le2,
        const float* __restrict__ W_dyn1, const float* __restrict__ b_dyn1,
        const float* __restrict__ W_dyn2, const float* __restrict__ b_dyn2,
        const float* __restrict__ log_Q, const float* __restrict__ eps,
        float* __restrict__ zout, float* __restrict__ kcl) {
    __shared__ alignas(16) _Float16 zSm[16][88];    // rows 0,1 live
    __shared__ alignas(16) _Float16 hidS[16][152];
    __shared__ alignas(16) _Float16 gS[16][88];
    __shared__ alignas(16) float stH[2][136];       // phase-A acc staging
    __shared__ alignas(16) float stG[2][72];
    __shared__ alignas(16) float stM[2][136];       // phase-B acc staging
    __shared__ alignas(16) float stMU[2][72];
    __shared__ float bmS[64], bpS[64], bmuS[64], bd1S[64], invQS[64];
    __shared__ float redK[4];

    const int tid = threadIdx.x;
    const int b = blockIdx.x >> 2, sq = blockIdx.x & 3, s0 = sq * 2;
    const int w = tid >> 6, l = tid & 63;
    const int lo = l & 15, hi = l >> 4;
    const bool prod = (lo < 2);         // producer lanes (valid D cols 0,1)

    // ---- zero f16 LDS (rows >=2 stay zero forever); fill const tables ----
    {
        _Float16* p1 = &zSm[0][0];
        _Float16* p2 = &hidS[0][0];
        _Float16* p3 = &gS[0][0];
        for (int i = tid; i < 16 * 88; i += 256) { p1[i] = (_Float16)0.f; p3[i] = (_Float16)0.f; }
        for (int i = tid; i < 16 * 152; i += 256) p2[i] = (_Float16)0.f;
    }
    if (tid < 64) {
        bmS[tid]   = b_le2[tid];
        bpS[tid]   = b_le2[64 + tid];
        bmuS[tid]  = b_dyn2[tid];
        bd1S[tid]  = b_dyn1[tid];
        invQS[tid] = 1.f / softplus_f(log_Q[tid]);
    }

    // ---- static weight fragments ----
    f16x8_t a1[2][2], a2[2][4], a3[2], a4[2];
    #pragma unroll
    for (int ct = 0; ct < 2; ++ct)
        #pragma unroll
        for (int kt = 0; kt < 2; ++kt) {
            f16x8_t f;
            #pragma unroll
            for (int e = 0; e < 8; ++e)
                f[e] = (_Float16)W_le1[(size_t)(128 + kt * 32 + 8 * hi + e) * 128 + (32 * w + 16 * ct + lo)];
            a1[ct][kt] = f;
        }
    #pragma unroll
    for (int ct = 0; ct < 2; ++ct) {
        const int col = (ct == 0 ? 16 * w : 64 + 16 * w) + lo;
        #pragma unroll
        for (int kt = 0; kt < 4; ++kt) {
            f16x8_t f;
            #pragma unroll
            for (int e = 0; e < 8; ++e)
                f[e] = (_Float16)W_le2[(size_t)(kt * 32 + 8 * hi + e) * 128 + col];
            a2[ct][kt] = f;
        }
    }
    #pragma unroll
    for (int kt = 0; kt < 2; ++kt) {
        f16x8_t f, g;
        #pragma unroll
        for (int e = 0; e < 8; ++e) {
            f[e] = (_Float16)W_dyn1[(size_t)(kt * 32 + 8 * hi + e) * 64 + (16 * w + lo)];
            g[e] = (_Float16)W_dyn2[(size_t)(kt * 32 + 8 * hi + e) * 64 + (16 * w + lo)];
        }
        a3[kt] = f; a4[kt] = g;
    }

    // ---- dense wave-local role mappings ----
    const int ha = l >> 5, hc = 32 * w + (l & 31);  // activation: sample,col
    const int ga2 = (l >> 4) & 1, gc = 16 * w + (l & 15);
    const int es = ga2, ec = gc;                    // epilogue: sample,col
    const float* ap = Aglob + ((size_t)b * T + 1) * 128 + hc;
    const float* ep = eps + (((size_t)(s0 + es)) * B + b) * 64 + ec;     // t=1
    float*       zp = zout + ((((size_t)(s0 + es)) * B + b) * T + 1) * 64 + ec;

    float klAcc = 0.f;      // lanes l<32; reduced once after the loop

    __syncthreads();
    // ---- stage z0 (2 samples) ----
    if (tid < 128) {
        int ss = tid >> 6, c6 = tid & 63;
        zSm[ss][c6] = (_Float16)zout[(((size_t)(s0 + ss) * B + b) * T + 0) * 64 + c6];
    }
    __syncthreads();

    // ---- software-pipelined prefetch (t=1) ----
    float aN = *ap;
    float eN = 0.f;
    if (l < 32) eN = *ep;

    for (int t = 1; t < T; ++t) {
        const float aC = aN, eC = eN;

        // next-step global prefetch (consumed next iteration)
        if (t < T - 1) {
            ap += 128; aN = *ap;
            if (l < 32) { ep += (size_t)S * B * 64; eN = *ep; }
        }

        // ---- phase A MFMAs: z@W1b ; z@Wd1 ----
        const f16x8_t bz0 = *(const f16x8_t*)&zSm[lo][8 * hi];
        const f16x8_t bz1 = *(const f16x8_t*)&zSm[lo][32 + 8 * hi];

        f32x4_t acc1a = {0.f,0.f,0.f,0.f}, acc1b = {0.f,0.f,0.f,0.f}, acc3 = {0.f,0.f,0.f,0.f};
        acc1a = __builtin_amdgcn_mfma_f32_16x16x32_f16(a1[0][0], bz0, acc1a, 0, 0, 0);
        acc1b = __builtin_amdgcn_mfma_f32_16x16x32_f16(a1[1][0], bz0, acc1b, 0, 0, 0);
        acc3  = __builtin_amdgcn_mfma_f32_16x16x32_f16(a3[0],    bz0, acc3,  0, 0, 0);
        acc1a = __builtin_amdgcn_mfma_f32_16x16x32_f16(a1[0][1], bz1, acc1a, 0, 0, 0);
        acc1b = __builtin_amdgcn_mfma_f32_16x16x32_f16(a1[1][1], bz1, acc1b, 0, 0, 0);
        acc3  = __builtin_amdgcn_mfma_f32_16x16x32_f16(a3[1],    bz1, acc3,  0, 0, 0);

        // wave-private staging (same-wave LDS ordering; no barrier)
        if (prod) {
            *(f32x4_t*)&stH[lo][32 * w + 4 * hi]      = acc1a;
            *(f32x4_t*)&stH[lo][32 * w + 16 + 4 * hi] = acc1b;
            *(f32x4_t*)&stG[lo][16 * w + 4 * hi]      = acc3;
        }
        asm volatile("" ::: "memory");

        // ---- dense activation (same wave consumes its own strip) ----
        hidS[ha][hc] = (_Float16)fast_tanh(stH[ha][hc] + aC);
        if (l < 32)
            gS[ga2][gc] = (_Float16)fast_tanh(stG[ga2][gc] + bd1S[gc]);
        __syncthreads();   // (1) hid/g visible cross-wave

        // ---- phase B MFMAs: hid@W2 ; g@Wd2 ----
        const f16x8_t bh0 = *(const f16x8_t*)&hidS[lo][ 0 + 8 * hi];
        const f16x8_t bh1 = *(const f16x8_t*)&hidS[lo][32 + 8 * hi];
        const f16x8_t bh2 = *(const f16x8_t*)&hidS[lo][64 + 8 * hi];
        const f16x8_t bh3 = *(const f16x8_t*)&hidS[lo][96 + 8 * hi];
        const f16x8_t bg0 = *(const f16x8_t*)&gS[lo][8 * hi];
        const f16x8_t bg1 = *(const f16x8_t*)&gS[lo][32 + 8 * hi];

        f32x4_t accm = {0.f,0.f,0.f,0.f}, accp = {0.f,0.f,0.f,0.f}, acc4 = {0.f,0.f,0.f,0.f};
        accm = __builtin_amdgcn_mfma_f32_16x16x32_f16(a2[0][0], bh0, accm, 0, 0, 0);
        accp = __builtin_amdgcn_mfma_f32_16x16x32_f16(a2[1][0], bh0, accp, 0, 0, 0);
        acc4 = __builtin_amdgcn_mfma_f32_16x16x32_f16(a4[0],    bg0, acc4, 0, 0, 0);
        accm = __builtin_amdgcn_mfma_f32_16x16x32_f16(a2[0][1], bh1, accm, 0, 0, 0);
        accp = __builtin_amdgcn_mfma_f32_16x16x32_f16(a2[1][1], bh1, accp, 0, 0, 0);
        acc4 = __builtin_amdgcn_mfma_f32_16x16x32_f16(a4[1],    bg1, acc4, 0, 0, 0);
        accm = __builtin_amdgcn_mfma_f32_16x16x32_f16(a2[0][2], bh2, accm, 0, 0, 0);
        accp = __builtin_amdgcn_mfma_f32_16x16x32_f16(a2[1][2], bh2, accp, 0, 0, 0);
        accm = __builtin_amdgcn_mfma_f32_16x16x32_f16(a2[0][3], bh3, accm, 0, 0, 0);
        accp = __builtin_amdgcn_mfma_f32_16x16x32_f16(a2[1][3], bh3, accp, 0, 0, 0);

        if (prod) {
            *(f32x4_t*)&stM[lo][16 * w + 4 * hi]       = accm;
            *(f32x4_t*)&stM[lo][64 + 16 * w + 4 * hi]  = accp;
            *(f32x4_t*)&stMU[lo][16 * w + 4 * hi]      = acc4;
        }
        asm volatile("" ::: "memory");

        // ---- dense epilogue + KL ACCUMULATION (lanes l<32) ----
        if (l < 32) {
            float m  = stM[es][ec] + bmS[ec];
            float P  = softplus_fast(stM[es][64 + ec] + bpS[ec]);
            float mu = stMU[es][ec] + bmuS[ec];
            float iq = invQS[ec];
            float z  = m + sqrtf(P) * eC;
            *zp = z; zp += 64;
            zSm[es][ec] = (_Float16)z;
            float d = m - mu;
            klAcc += (P + d * d) * iq - __logf(P * iq) - 1.f;
        }
        __syncthreads();   // (2) zSm visible for next step
    }

    // ---- ONE reduction for the whole kernel ----
    float kv = klAcc;          // lanes l<32
    kv += __shfl_down(kv, 16);
    kv += __shfl_down(kv, 8);
    kv += __shfl_down(kv, 4);
    kv += __shfl_down(kv, 2);
    kv += __shfl_down(kv, 1);
    if (l == 0) redK[w] = kv;
    __syncthreads();
    if (tid == 0)
        kcl[blockIdx.x] = 0.0625f * (redK[0] + redK[1] + redK[2] + redK[3]);
}

// ---------------------------------------------------------------------------
// Kernel P2 (MFMA throughput): projection z@C + Poisson ell + m_stat.
// 512 blocks = (b = bid>>2, T-quarter tq = bid&3); 32 t-pairs per block.
// B-op packs 16 cols = 8 samples x 2 timesteps (full MFMA utilization).
// Fragment conventions as kA/kC (verified). ell register-accumulated,
// one block reduction at end -> kel[bid]. m_stat fused (kM deleted).
// ---------------------------------------------------------------------------
__global__ __launch_bounds__(256) void kP2(
        const float* __restrict__ zin, const float* __restrict__ Cmat,
        const float* __restrict__ b_c, const float* __restrict__ yglob,
        float* __restrict__ m_stat, float* __restrict__ kel) {
    __shared__ alignas(16) _Float16 zP[16][72];    // [col=(2s+tidx)][l]
    __shared__ alignas(16) float yP[256];          // rows t0,t0+1
    __shared__ float red4[4];

    const int tid = threadIdx.x;
    const int w = tid >> 6, l = tid & 63;
    const int lo = l & 15, hi = l >> 4;
    const int b = blockIdx.x >> 2, tq = blockIdx.x & 3;
    const int tbase = tq * 64;

    // ---- C fragments: wave w covers outcols 32w..32w+32 (32 VGPRs) ----
    f16x8_t aC[2][2];
    #pragma unroll
    for (int ct = 0; ct < 2; ++ct)
        #pragma unroll
        for (int kt = 0; kt < 2; ++kt) {
            f16x8_t f;
            #pragma unroll
            for (int e = 0; e < 8; ++e)
                f[e] = (_Float16)Cmat[(size_t)(kt * 32 + 8 * hi + e) * 128 + (32 * w + 16 * ct + lo)];
            aC[ct][kt] = f;
        }
    f32x4_t bc[2];
    #pragma unroll
    for (int ct = 0; ct < 2; ++ct)
        #pragma unroll
        for (int r = 0; r < 4; ++r)
            bc[ct][r] = b_c[32 * w + 16 * ct + 4 * hi + r];

    float ellAcc = 0.f;

    for (int j = 0; j < 32; ++j) {
        const int t0 = tbase + 2 * j;
        __syncthreads();   // protect LDS reuse across iterations
        // ---- load z pair (8s x 2t x 64l) -> f16 LDS; y pair -> f32 LDS ----
        {
            int i = tid;                        // 256 float4s
            int s = i >> 5, rem = i & 31;
            int tdx = rem >> 4, l4 = (rem & 15) * 4;
            f32x4_t v = *(const f32x4_t*)&zin[(((size_t)s * B + b) * T + t0 + tdx) * 64 + l4];
            f16x4_t h4;
            h4[0] = (_Float16)v[0]; h4[1] = (_Float16)v[1];
            h4[2] = (_Float16)v[2]; h4[3] = (_Float16)v[3];
            *(f16x4_t*)&zP[s * 2 + tdx][l4] = h4;
            yP[tid] = yglob[((size_t)b * T + t0) * 128 + tid];
        }
        __syncthreads();

        // ---- m_stat (threads 0..127): mean over s ----
        if (tid < 128) {
            int tdx = tid >> 6, ll = tid & 63;
            float acc = 0.f;
            #pragma unroll
            for (int s = 0; s < 8; ++s) acc += (float)zP[s * 2 + tdx][ll];
            m_stat[((size_t)b * T + t0 + tdx) * 64 + ll] = 0.125f * acc;
        }

        // ---- MFMAs: D[outcol][(s,t)] ----
        const f16x8_t bz0 = *(const f16x8_t*)&zP[lo][8 * hi];
        const f16x8_t bz1 = *(const f16x8_t*)&zP[lo][32 + 8 * hi];
        f32x4_t acc0 = {0.f,0.f,0.f,0.f}, acc1 = {0.f,0.f,0.f,0.f};
        acc0 = __builtin_amdgcn_mfma_f32_16x16x32_f16(aC[0][0], bz0, acc0, 0, 0, 0);
        acc1 = __builtin_amdgcn_mfma_f32_16x16x32_f16(aC[1][0], bz0, acc1, 0, 0, 0);
        acc0 = __builtin_amdgcn_mfma_f32_16x16x32_f16(aC[0][1], bz1, acc0, 0, 0, 0);
        acc1 = __builtin_amdgcn_mfma_f32_16x16x32_f16(aC[1][1], bz1, acc1, 0, 0, 0);

        // ---- Poisson epilogue: lane owns (s = lo>>1, tdx = lo&1) ----
        {
            const int tdx = lo & 1;
            float te = 0.f;
            #pragma unroll
            for (int r = 0; r < 4; ++r) {
                int n0 = 32 * w + 4 * hi + r;
                float lr0 = acc0[r] + bc[0][r];
                float yv0 = yP[tdx * 128 + n0];
                te += yv0 * lr0 - __expf(lr0);
                int n1 = n0 + 16;
                float lr1 = acc1[r] + bc[1][r];
                float yv1 = yP[tdx * 128 + n1];
                te += yv1 * lr1 - __expf(lr1);
                if (lo < 2) te -= 8.f * (gaOf(yv0) + gaOf(yv1));   // once per (t,n), undo /8
            }
            ellAcc += 0.125f * te;
        }
    }

    // ---- block reduction -> kel[bid] ----
    float ev = ellAcc;
    ev += __shfl_down(ev, 32);
    ev += __shfl_down(ev, 16);
    ev += __shfl_down(ev, 8);
    ev += __shfl_down(ev, 4);
    ev += __shfl_down(ev, 2);
    ev += __shfl_down(ev, 1);
    if (l == 0) red4[w] = ev;
    __syncthreads();
    if (tid == 0) kel[blockIdx.x] = red4[0] + red4[1] + red4[2] + red4[3];
}

// ---------------------------------------------------------------------------
// Kernel R: loss = ( sum_b kl0[b] + sum_blk kcl - sum_blk kel ) / B
// ---------------------------------------------------------------------------
__global__ __launch_bounds__(256) void kR(
        const float* __restrict__ kl0w, const float* __restrict__ kcl,
        const float* __restrict__ kel, float* __restrict__ out0) {
    __shared__ float red4[4];
    const int tid = threadIdx.x;
    float acc = 0.f;
    #pragma unroll
    for (int ii = 0; ii < 2; ii++) {
        int i = tid + ii * 256;
        acc += kcl[i] - kel[i];
    }
    if (tid < 128) acc += kl0w[tid];
    #pragma unroll
    for (int off = 32; off; off >>= 1) acc += __shfl_down(acc, off);
    if ((tid & 63) == 0) red4[tid >> 6] = acc;
    __syncthreads();
    if (tid == 0) out0[0] = (red4[0] + red4[1] + red4[2] + red4[3]) * (1.0f / B);
}

// ---------------------------------------------------------------------------
extern "C" void kernel_launch(void* const* d_in, const int* in_sizes, int n_in,
                              void* d_out, int out_size, void* d_ws, size_t ws_size,
                              hipStream_t stream) {
    const float* y      = (const float*)d_in[0];
    const float* W_be   = (const float*)d_in[2];
    const float* b_be   = (const float*)d_in[3];
    const float* W_ic   = (const float*)d_in[4];
    const float* b_ic   = (const float*)d_in[5];
    const float* W_le1  = (const float*)d_in[6];
    const float* b_le1  = (const float*)d_in[7];
    const float* W_le2  = (const float*)d_in[8];
    const float* b_le2  = (const float*)d_in[9];
    const float* W_dyn1 = (const float*)d_in[10];
    const float* b_dyn1 = (const float*)d_in[11];
    const float* W_dyn2 = (const float*)d_in[12];
    const float* b_dyn2 = (const float*)d_in[13];
    const float* C      = (const float*)d_in[14];
    const float* b_c    = (const float*)d_in[15];
    const float* log_Q  = (const float*)d_in[16];
    const float* m_0    = (const float*)d_in[17];
    const float* log_Q_0= (const float*)d_in[18];
    const float* eps0   = (const float*)d_in[19];
    const float* eps    = (const float*)d_in[20];

    float* out = (float*)d_out;
    float* zo  = out + 1;
    float* ms  = out + 1 + (size_t)S * B * T * L;

    float* ws   = (float*)d_ws;
    float* kl0w = ws;                                      // B
    float* kcl  = kl0w + B;                                // 512
    float* kel  = kcl + 512;                               // 512
    float* h0   = kel + 512;                               // B*128
    float* A    = h0 + (size_t)B * 128;                    // B*T*128

    kA<<<1024, 256, 0, stream>>>(y, W_be, b_be, W_le1, b_le1, A, h0);
    kB<<<128, 128, 0, stream>>>(h0, W_ic, b_ic, m_0, log_Q_0, eps0, zo, kl0w);
    kC<<<512, 256, 0, stream>>>(A, W_le1, W_le2, b_le2, W_dyn1, b_dyn1,
                                W_dyn2, b_dyn2, log_Q, eps, zo, kcl);
    kP2<<<512, 256, 0, stream>>>(zo, C, b_c, y, ms, kel);
    kR<<<1, 256, 0, stream>>>(kl0w, kcl, kel, out);
}

// Round 17
// 341.088 us; speedup vs baseline: 1.7242x; 1.0075x over previous
//
#include <hip/hip_runtime.h>

// Problem constants
constexpr int S = 8, B = 128, T = 256, N = 128;
constexpr int L = 64, Hh = 128, Hd = 64, Hl = 128;
constexpr int BT = B * T;

#define DEVFN __device__ __forceinline__

typedef float    f32x4_t __attribute__((ext_vector_type(4)));
typedef _Float16 f16x8_t __attribute__((ext_vector_type(8)));
typedef _Float16 f16x4_t __attribute__((ext_vector_type(4)));

DEVFN float softplus_f(float x) {            // accurate (prologue only)
    return (x > 0.f) ? (x + log1pf(expf(-x))) : log1pf(expf(x));
}
DEVFN float softplus_fast(float x) {         // branchless, native trans
    return fmaxf(x, 0.f) + __logf(1.f + __expf(-fabsf(x)));
}
DEVFN float fast_tanh(float x) {
    float ex = __builtin_exp2f(x * 2.885390081777927f);
    return 1.f - 2.f / (ex + 1.f);
}
DEVFN float gaOf(float yv) {                 // gammaln(y+1), y in {0..4}
    int yi = (int)yv;
    return (yi < 2) ? 0.f
         : ((yi == 2) ? 0.6931471805599453f
         : ((yi == 3) ? 1.791759469228055f : 3.1780538303479458f));
}

// ---------------------------------------------------------------------------
// Kernel A (MFMA): per (b,t) row: h = tanh(y@W_be + b_be); A = h@W1a + b_le1.
// ---------------------------------------------------------------------------
__global__ __launch_bounds__(256) void kA(
        const float* __restrict__ y,
        const float* __restrict__ W_be, const float* __restrict__ b_be,
        const float* __restrict__ W_le1, const float* __restrict__ b_le1,
        float* __restrict__ A, float* __restrict__ h0) {
    __shared__ alignas(16) _Float16 yS[32][136];   // [row][n] pad 68 dw
    __shared__ alignas(16) _Float16 hS[32][152];   // pad 76 dw
    __shared__ alignas(16) float    st[32][136];   // f32 acc staging
    __shared__ float bbeS[128];

    const int tid = threadIdx.x;
    const int w = tid >> 6, l = tid & 63;
    const int lo = l & 15, hi = l >> 4;
    const int bt0 = blockIdx.x * 32;

    if (tid < 128) bbeS[tid] = b_be[tid];

    // ---- load y rows -> f16 LDS ----
    {
        const float4* y4 = (const float4*)(y + (size_t)bt0 * 128);
        #pragma unroll
        for (int k = 0; k < 4; ++k) {
            int i = k * 256 + tid;              // 1024 float4s
            float4 v = y4[i];
            int row = i >> 5, c4 = (i & 31) * 4;
            f16x4_t h4;
            h4[0] = (_Float16)v.x; h4[1] = (_Float16)v.y;
            h4[2] = (_Float16)v.z; h4[3] = (_Float16)v.w;
            *(f16x4_t*)&yS[row][c4] = h4;
        }
    }

    // ---- weight fragments (64 VGPRs) ----
    f16x8_t awb[2][4], awa[2][4];
    #pragma unroll
    for (int ct = 0; ct < 2; ++ct)
        #pragma unroll
        for (int kt = 0; kt < 4; ++kt) {
            f16x8_t f, g;
            #pragma unroll
            for (int e = 0; e < 8; ++e) {
                size_t off = (size_t)(kt * 32 + 8 * hi + e) * 128 + (32 * w + 16 * ct + lo);
                f[e] = (_Float16)W_be[off];
                g[e] = (_Float16)W_le1[off];    // rows 0..127 = W1a
            }
            awb[ct][kt] = f; awa[ct][kt] = g;
        }
    const f32x4_t bl0 = *(const f32x4_t*)&b_le1[32 * w + 4 * hi];
    const f32x4_t bl1 = *(const f32x4_t*)&b_le1[32 * w + 16 + 4 * hi];
    __syncthreads();

    // ---- GEMM1: h_pre = y @ W_be ----
    #pragma unroll
    for (int rt = 0; rt < 2; ++rt) {
        f32x4_t acc0 = {0.f,0.f,0.f,0.f}, acc1 = {0.f,0.f,0.f,0.f};
        #pragma unroll
        for (int kt = 0; kt < 4; ++kt) {
            const f16x8_t bf = *(const f16x8_t*)&yS[16 * rt + lo][kt * 32 + 8 * hi];
            acc0 = __builtin_amdgcn_mfma_f32_16x16x32_f16(awb[0][kt], bf, acc0, 0, 0, 0);
            acc1 = __builtin_amdgcn_mfma_f32_16x16x32_f16(awb[1][kt], bf, acc1, 0, 0, 0);
        }
        *(f32x4_t*)&st[16 * rt + lo][32 * w + 4 * hi]      = acc0;
        *(f32x4_t*)&st[16 * rt + lo][32 * w + 16 + 4 * hi] = acc1;
    }
    __syncthreads();

    // ---- dense tanh pass: 16 values/thread ----
    {
        const int trow = tid >> 3, cb = (tid & 7) * 16;
        const bool isH0 = ((bt0 & 255) == 0) && (trow == 0);
        float* h0p = h0 + (size_t)(bt0 >> 8) * 128;
        #pragma unroll
        for (int j = 0; j < 16; ++j) {
            float hv = fast_tanh(st[trow][cb + j] + bbeS[cb + j]);
            hS[trow][cb + j] = (_Float16)hv;
            if (isH0) h0p[cb + j] = hv;
        }
    }
    __syncthreads();

    // ---- GEMM2: A = h @ W1a + b_le1 ----
    #pragma unroll
    for (int rt = 0; rt < 2; ++rt) {
        f32x4_t acc0 = {0.f,0.f,0.f,0.f}, acc1 = {0.f,0.f,0.f,0.f};
        #pragma unroll
        for (int kt = 0; kt < 4; ++kt) {
            const f16x8_t bf = *(const f16x8_t*)&hS[16 * rt + lo][kt * 32 + 8 * hi];
            acc0 = __builtin_amdgcn_mfma_f32_16x16x32_f16(awa[0][kt], bf, acc0, 0, 0, 0);
            acc1 = __builtin_amdgcn_mfma_f32_16x16x32_f16(awa[1][kt], bf, acc1, 0, 0, 0);
        }
        acc0 += bl0; acc1 += bl1;
        float* Ar = A + (size_t)(bt0 + 16 * rt + lo) * 128;
        *(f32x4_t*)&Ar[32 * w + 4 * hi]      = acc0;
        *(f32x4_t*)&Ar[32 * w + 16 + 4 * hi] = acc1;
    }
}

// ---------------------------------------------------------------------------
// Kernel C (R17 = R16 + kB fused into prologue). 512 blocks = (b, sq).
// Prologue: each block computes mp0 = h0[b]@W_ic + b_ic (4x redundant,
// trivial), samples its own 2 z0 (writes zout t=0 + zSm directly — no
// global round-trip), and sq==0/es==0 lanes inject kl0 into klAcc (x8 to
// cancel the final 0.0625 scale down to kl0's 0.5 coefficient).
// ---------------------------------------------------------------------------
__global__ __launch_bounds__(256) void kC(
        const float* __restrict__ Aglob,
        const float* __restrict__ W_le1, const float* __restrict__ W_le2,
        const float* __restrict__ b_le2,
        const float* __restrict__ W_dyn1, const float* __restrict__ b_dyn1,
        const float* __restrict__ W_dyn2, const float* __restrict__ b_dyn2,
        const float* __restrict__ log_Q, const float* __restrict__ eps,
        const float* __restrict__ h0g, const float* __restrict__ W_ic,
        const float* __restrict__ b_ic, const float* __restrict__ m_0,
        const float* __restrict__ log_Q_0, const float* __restrict__ eps0,
        float* __restrict__ zout, float* __restrict__ kcl) {
    __shared__ alignas(16) _Float16 zSm[16][88];    // rows 0,1 live
    __shared__ alignas(16) _Float16 hidS[16][152];
    __shared__ alignas(16) _Float16 gS[16][88];
    __shared__ alignas(16) float stH[2][136];       // phase-A acc staging
    __shared__ alignas(16) float stG[2][72];
    __shared__ alignas(16) float stM[2][136];       // phase-B acc staging
    __shared__ alignas(16) float stMU[2][72];
    __shared__ float bmS[64], bpS[64], bmuS[64], bd1S[64], invQS[64];
    __shared__ float h0S[128], mpS[128];
    __shared__ float redK[4];

    const int tid = threadIdx.x;
    const int b = blockIdx.x >> 2, sq = blockIdx.x & 3, s0 = sq * 2;
    const int w = tid >> 6, l = tid & 63;
    const int lo = l & 15, hi = l >> 4;
    const bool prod = (lo < 2);         // producer lanes (valid D cols 0,1)

    // ---- zero f16 LDS (rows >=2 stay zero forever); fill const tables ----
    {
        _Float16* p1 = &zSm[0][0];
        _Float16* p2 = &hidS[0][0];
        _Float16* p3 = &gS[0][0];
        for (int i = tid; i < 16 * 88; i += 256) { p1[i] = (_Float16)0.f; p3[i] = (_Float16)0.f; }
        for (int i = tid; i < 16 * 152; i += 256) p2[i] = (_Float16)0.f;
    }
    if (tid < 64) {
        bmS[tid]   = b_le2[tid];
        bpS[tid]   = b_le2[64 + tid];
        bmuS[tid]  = b_dyn2[tid];
        bd1S[tid]  = b_dyn1[tid];
        invQS[tid] = 1.f / softplus_f(log_Q[tid]);
    }
    if (tid < 128) h0S[tid] = h0g[(size_t)b * 128 + tid];

    // ---- static weight fragments ----
    f16x8_t a1[2][2], a2[2][4], a3[2], a4[2];
    #pragma unroll
    for (int ct = 0; ct < 2; ++ct)
        #pragma unroll
        for (int kt = 0; kt < 2; ++kt) {
            f16x8_t f;
            #pragma unroll
            for (int e = 0; e < 8; ++e)
                f[e] = (_Float16)W_le1[(size_t)(128 + kt * 32 + 8 * hi + e) * 128 + (32 * w + 16 * ct + lo)];
            a1[ct][kt] = f;
        }
    #pragma unroll
    for (int ct = 0; ct < 2; ++ct) {
        const int col = (ct == 0 ? 16 * w : 64 + 16 * w) + lo;
        #pragma unroll
        for (int kt = 0; kt < 4; ++kt) {
            f16x8_t f;
            #pragma unroll
            for (int e = 0; e < 8; ++e)
                f[e] = (_Float16)W_le2[(size_t)(kt * 32 + 8 * hi + e) * 128 + col];
            a2[ct][kt] = f;
        }
    }
    #pragma unroll
    for (int kt = 0; kt < 2; ++kt) {
        f16x8_t f, g;
        #pragma unroll
        for (int e = 0; e < 8; ++e) {
            f[e] = (_Float16)W_dyn1[(size_t)(kt * 32 + 8 * hi + e) * 64 + (16 * w + lo)];
            g[e] = (_Float16)W_dyn2[(size_t)(kt * 32 + 8 * hi + e) * 64 + (16 * w + lo)];
        }
        a3[kt] = f; a4[kt] = g;
    }

    // ---- dense wave-local role mappings ----
    const int ha = l >> 5, hc = 32 * w + (l & 31);  // activation: sample,col
    const int ga2 = (l >> 4) & 1, gc = 16 * w + (l & 15);
    const int es = ga2, ec = gc;                    // epilogue: sample,col
    const float* ap = Aglob + ((size_t)b * T + 1) * 128 + hc;
    const float* ep = eps + (((size_t)(s0 + es)) * B + b) * 64 + ec;     // t=1
    float*       zp = zout + ((((size_t)(s0 + es)) * B + b) * T + 1) * 64 + ec;

    float klAcc = 0.f;      // lanes l<32; reduced once after the loop

    __syncthreads();        // h0S + const tables + zero-init visible

    // ---- fused kB: mp0 = h0 @ W_ic + b_ic (threads 0..127) ----
    if (tid < 128) {
        float acc = b_ic[tid];
        #pragma unroll 8
        for (int k = 0; k < 128; ++k) acc += h0S[k] * W_ic[(size_t)k * 128 + tid];
        mpS[tid] = acc;
    }
    __syncthreads();        // mpS visible

    // ---- z0 sampling + kl0 (epilogue lane mapping) ----
    if (l < 32) {
        float m0v = mpS[ec];
        float P0  = softplus_f(mpS[64 + ec]);
        float e0  = eps0[(((size_t)(s0 + es)) * B + b) * 64 + ec];
        float z0  = m0v + sqrtf(P0) * e0;
        zout[((((size_t)(s0 + es)) * B + b) * T + 0) * 64 + ec] = z0;
        zSm[es][ec] = (_Float16)z0;
        if (sq == 0 && es == 0) {
            float Q0 = softplus_f(log_Q_0[ec]);
            float d0 = m0v - m_0[ec];
            klAcc += 8.f * (logf(Q0) - logf(P0) + (P0 + d0 * d0) / Q0 - 1.f);
        }
    }
    __syncthreads();        // zSm visible

    // ---- software-pipelined prefetch (t=1) ----
    float aN = *ap;
    float eN = 0.f;
    if (l < 32) eN = *ep;

    for (int t = 1; t < T; ++t) {
        const float aC = aN, eC = eN;

        // next-step global prefetch (consumed next iteration)
        if (t < T - 1) {
            ap += 128; aN = *ap;
            if (l < 32) { ep += (size_t)S * B * 64; eN = *ep; }
        }

        // ---- phase A MFMAs: z@W1b ; z@Wd1 ----
        const f16x8_t bz0 = *(const f16x8_t*)&zSm[lo][8 * hi];
        const f16x8_t bz1 = *(const f16x8_t*)&zSm[lo][32 + 8 * hi];

        f32x4_t acc1a = {0.f,0.f,0.f,0.f}, acc1b = {0.f,0.f,0.f,0.f}, acc3 = {0.f,0.f,0.f,0.f};
        acc1a = __builtin_amdgcn_mfma_f32_16x16x32_f16(a1[0][0], bz0, acc1a, 0, 0, 0);
        acc1b = __builtin_amdgcn_mfma_f32_16x16x32_f16(a1[1][0], bz0, acc1b, 0, 0, 0);
        acc3  = __builtin_amdgcn_mfma_f32_16x16x32_f16(a3[0],    bz0, acc3,  0, 0, 0);
        acc1a = __builtin_amdgcn_mfma_f32_16x16x32_f16(a1[0][1], bz1, acc1a, 0, 0, 0);
        acc1b = __builtin_amdgcn_mfma_f32_16x16x32_f16(a1[1][1], bz1, acc1b, 0, 0, 0);
        acc3  = __builtin_amdgcn_mfma_f32_16x16x32_f16(a3[1],    bz1, acc3,  0, 0, 0);

        // wave-private staging (same-wave LDS ordering; no barrier)
        if (prod) {
            *(f32x4_t*)&stH[lo][32 * w + 4 * hi]      = acc1a;
            *(f32x4_t*)&stH[lo][32 * w + 16 + 4 * hi] = acc1b;
            *(f32x4_t*)&stG[lo][16 * w + 4 * hi]      = acc3;
        }
        asm volatile("" ::: "memory");

        // ---- dense activation (same wave consumes its own strip) ----
        hidS[ha][hc] = (_Float16)fast_tanh(stH[ha][hc] + aC);
        if (l < 32)
            gS[ga2][gc] = (_Float16)fast_tanh(stG[ga2][gc] + bd1S[gc]);
        __syncthreads();   // (1) hid/g visible cross-wave

        // ---- phase B MFMAs: hid@W2 ; g@Wd2 ----
        const f16x8_t bh0 = *(const f16x8_t*)&hidS[lo][ 0 + 8 * hi];
        const f16x8_t bh1 = *(const f16x8_t*)&hidS[lo][32 + 8 * hi];
        const f16x8_t bh2 = *(const f16x8_t*)&hidS[lo][64 + 8 * hi];
        const f16x8_t bh3 = *(const f16x8_t*)&hidS[lo][96 + 8 * hi];
        const f16x8_t bg0 = *(const f16x8_t*)&gS[lo][8 * hi];
        const f16x8_t bg1 = *(const f16x8_t*)&gS[lo][32 + 8 * hi];

        f32x4_t accm = {0.f,0.f,0.f,0.f}, accp = {0.f,0.f,0.f,0.f}, acc4 = {0.f,0.f,0.f,0.f};
        accm = __builtin_amdgcn_mfma_f32_16x16x32_f16(a2[0][0], bh0, accm, 0, 0, 0);
        accp = __builtin_amdgcn_mfma_f32_16x16x32_f16(a2[1][0], bh0, accp, 0, 0, 0);
        acc4 = __builtin_amdgcn_mfma_f32_16x16x32_f16(a4[0],    bg0, acc4, 0, 0, 0);
        accm = __builtin_amdgcn_mfma_f32_16x16x32_f16(a2[0][1], bh1, accm, 0, 0, 0);
        accp = __builtin_amdgcn_mfma_f32_16x16x32_f16(a2[1][1], bh1, accp, 0, 0, 0);
        acc4 = __builtin_amdgcn_mfma_f32_16x16x32_f16(a4[1],    bg1, acc4, 0, 0, 0);
        accm = __builtin_amdgcn_mfma_f32_16x16x32_f16(a2[0][2], bh2, accm, 0, 0, 0);
        accp = __builtin_amdgcn_mfma_f32_16x16x32_f16(a2[1][2], bh2, accp, 0, 0, 0);
        accm = __builtin_amdgcn_mfma_f32_16x16x32_f16(a2[0][3], bh3, accm, 0, 0, 0);
        accp = __builtin_amdgcn_mfma_f32_16x16x32_f16(a2[1][3], bh3, accp, 0, 0, 0);

        if (prod) {
            *(f32x4_t*)&stM[lo][16 * w + 4 * hi]       = accm;
            *(f32x4_t*)&stM[lo][64 + 16 * w + 4 * hi]  = accp;
            *(f32x4_t*)&stMU[lo][16 * w + 4 * hi]      = acc4;
        }
        asm volatile("" ::: "memory");

        // ---- dense epilogue + KL ACCUMULATION (lanes l<32) ----
        if (l < 32) {
            float m  = stM[es][ec] + bmS[ec];
            float P  = softplus_fast(stM[es][64 + ec] + bpS[ec]);
            float mu = stMU[es][ec] + bmuS[ec];
            float iq = invQS[ec];
            float z  = m + sqrtf(P) * eC;
            *zp = z; zp += 64;
            zSm[es][ec] = (_Float16)z;
            float d = m - mu;
            klAcc += (P + d * d) * iq - __logf(P * iq) - 1.f;
        }
        __syncthreads();   // (2) zSm visible for next step
    }

    // ---- ONE reduction for the whole kernel ----
    float kv = klAcc;          // lanes l<32
    kv += __shfl_down(kv, 16);
    kv += __shfl_down(kv, 8);
    kv += __shfl_down(kv, 4);
    kv += __shfl_down(kv, 2);
    kv += __shfl_down(kv, 1);
    if (l == 0) redK[w] = kv;
    __syncthreads();
    if (tid == 0)
        kcl[blockIdx.x] = 0.0625f * (redK[0] + redK[1] + redK[2] + redK[3]);
}

// ---------------------------------------------------------------------------
// Kernel P2 (MFMA throughput): projection z@C + Poisson ell + m_stat.
// ---------------------------------------------------------------------------
__global__ __launch_bounds__(256) void kP2(
        const float* __restrict__ zin, const float* __restrict__ Cmat,
        const float* __restrict__ b_c, const float* __restrict__ yglob,
        float* __restrict__ m_stat, float* __restrict__ kel) {
    __shared__ alignas(16) _Float16 zP[16][72];    // [col=(2s+tidx)][l]
    __shared__ alignas(16) float yP[256];          // rows t0,t0+1
    __shared__ float red4[4];

    const int tid = threadIdx.x;
    const int w = tid >> 6, l = tid & 63;
    const int lo = l & 15, hi = l >> 4;
    const int b = blockIdx.x >> 2, tq = blockIdx.x & 3;
    const int tbase = tq * 64;

    // ---- C fragments: wave w covers outcols 32w..32w+32 (32 VGPRs) ----
    f16x8_t aC[2][2];
    #pragma unroll
    for (int ct = 0; ct < 2; ++ct)
        #pragma unroll
        for (int kt = 0; kt < 2; ++kt) {
            f16x8_t f;
            #pragma unroll
            for (int e = 0; e < 8; ++e)
                f[e] = (_Float16)Cmat[(size_t)(kt * 32 + 8 * hi + e) * 128 + (32 * w + 16 * ct + lo)];
            aC[ct][kt] = f;
        }
    f32x4_t bc[2];
    #pragma unroll
    for (int ct = 0; ct < 2; ++ct)
        #pragma unroll
        for (int r = 0; r < 4; ++r)
            bc[ct][r] = b_c[32 * w + 16 * ct + 4 * hi + r];

    float ellAcc = 0.f;

    for (int j = 0; j < 32; ++j) {
        const int t0 = tbase + 2 * j;
        __syncthreads();   // protect LDS reuse across iterations
        // ---- load z pair (8s x 2t x 64l) -> f16 LDS; y pair -> f32 LDS ----
        {
            int i = tid;                        // 256 float4s
            int s = i >> 5, rem = i & 31;
            int tdx = rem >> 4, l4 = (rem & 15) * 4;
            f32x4_t v = *(const f32x4_t*)&zin[(((size_t)s * B + b) * T + t0 + tdx) * 64 + l4];
            f16x4_t h4;
            h4[0] = (_Float16)v[0]; h4[1] = (_Float16)v[1];
            h4[2] = (_Float16)v[2]; h4[3] = (_Float16)v[3];
            *(f16x4_t*)&zP[s * 2 + tdx][l4] = h4;
            yP[tid] = yglob[((size_t)b * T + t0) * 128 + tid];
        }
        __syncthreads();

        // ---- m_stat (threads 0..127): mean over s ----
        if (tid < 128) {
            int tdx = tid >> 6, ll = tid & 63;
            float acc = 0.f;
            #pragma unroll
            for (int s = 0; s < 8; ++s) acc += (float)zP[s * 2 + tdx][ll];
            m_stat[((size_t)b * T + t0 + tdx) * 64 + ll] = 0.125f * acc;
        }

        // ---- MFMAs: D[outcol][(s,t)] ----
        const f16x8_t bz0 = *(const f16x8_t*)&zP[lo][8 * hi];
        const f16x8_t bz1 = *(const f16x8_t*)&zP[lo][32 + 8 * hi];
        f32x4_t acc0 = {0.f,0.f,0.f,0.f}, acc1 = {0.f,0.f,0.f,0.f};
        acc0 = __builtin_amdgcn_mfma_f32_16x16x32_f16(aC[0][0], bz0, acc0, 0, 0, 0);
        acc1 = __builtin_amdgcn_mfma_f32_16x16x32_f16(aC[1][0], bz0, acc1, 0, 0, 0);
        acc0 = __builtin_amdgcn_mfma_f32_16x16x32_f16(aC[0][1], bz1, acc0, 0, 0, 0);
        acc1 = __builtin_amdgcn_mfma_f32_16x16x32_f16(aC[1][1], bz1, acc1, 0, 0, 0);

        // ---- Poisson epilogue: lane owns (s = lo>>1, tdx = lo&1) ----
        {
            const int tdx = lo & 1;
            float te = 0.f;
            #pragma unroll
            for (int r = 0; r < 4; ++r) {
                int n0 = 32 * w + 4 * hi + r;
                float lr0 = acc0[r] + bc[0][r];
                float yv0 = yP[tdx * 128 + n0];
                te += yv0 * lr0 - __expf(lr0);
                int n1 = n0 + 16;
                float lr1 = acc1[r] + bc[1][r];
                float yv1 = yP[tdx * 128 + n1];
                te += yv1 * lr1 - __expf(lr1);
                if (lo < 2) te -= 8.f * (gaOf(yv0) + gaOf(yv1));   // once per (t,n), undo /8
            }
            ellAcc += 0.125f * te;
        }
    }

    // ---- block reduction -> kel[bid] ----
    float ev = ellAcc;
    ev += __shfl_down(ev, 32);
    ev += __shfl_down(ev, 16);
    ev += __shfl_down(ev, 8);
    ev += __shfl_down(ev, 4);
    ev += __shfl_down(ev, 2);
    ev += __shfl_down(ev, 1);
    if (l == 0) red4[w] = ev;
    __syncthreads();
    if (tid == 0) kel[blockIdx.x] = red4[0] + red4[1] + red4[2] + red4[3];
}

// ---------------------------------------------------------------------------
// Kernel R: loss = ( sum_blk kcl - sum_blk kel ) / B
// ---------------------------------------------------------------------------
__global__ __launch_bounds__(256) void kR(
        const float* __restrict__ kcl, const float* __restrict__ kel,
        float* __restrict__ out0) {
    __shared__ float red4[4];
    const int tid = threadIdx.x;
    float acc = 0.f;
    #pragma unroll
    for (int ii = 0; ii < 2; ii++) {
        int i = tid + ii * 256;
        acc += kcl[i] - kel[i];
    }
    #pragma unroll
    for (int off = 32; off; off >>= 1) acc += __shfl_down(acc, off);
    if ((tid & 63) == 0) red4[tid >> 6] = acc;
    __syncthreads();
    if (tid == 0) out0[0] = (red4[0] + red4[1] + red4[2] + red4[3]) * (1.0f / B);
}

// ---------------------------------------------------------------------------
extern "C" void kernel_launch(void* const* d_in, const int* in_sizes, int n_in,
                              void* d_out, int out_size, void* d_ws, size_t ws_size,
                              hipStream_t stream) {
    const float* y      = (const float*)d_in[0];
    const float* W_be   = (const float*)d_in[2];
    const float* b_be   = (const float*)d_in[3];
    const float* W_ic   = (const float*)d_in[4];
    const float* b_ic   = (const float*)d_in[5];
    const float* W_le1  = (const float*)d_in[6];
    const float* b_le1  = (const float*)d_in[7];
    const float* W_le2  = (const float*)d_in[8];
    const float* b_le2  = (const float*)d_in[9];
    const float* W_dyn1 = (const float*)d_in[10];
    const float* b_dyn1 = (const float*)d_in[11];
    const float* W_dyn2 = (const float*)d_in[12];
    const float* b_dyn2 = (const float*)d_in[13];
    const float* C      = (const float*)d_in[14];
    const float* b_c    = (const float*)d_in[15];
    const float* log_Q  = (const float*)d_in[16];
    const float* m_0    = (const float*)d_in[17];
    const float* log_Q_0= (const float*)d_in[18];
    const float* eps0   = (const float*)d_in[19];
    const float* eps    = (const float*)d_in[20];

    float* out = (float*)d_out;
    float* zo  = out + 1;
    float* ms  = out + 1 + (size_t)S * B * T * L;

    float* ws   = (float*)d_ws;
    float* kcl  = ws;                                      // 512
    float* kel  = kcl + 512;                               // 512
    float* h0   = kel + 512;                               // B*128
    float* A    = h0 + (size_t)B * 128;                    // B*T*128

    kA<<<1024, 256, 0, stream>>>(y, W_be, b_be, W_le1, b_le1, A, h0);
    kC<<<512, 256, 0, stream>>>(A, W_le1, W_le2, b_le2, W_dyn1, b_dyn1,
                                W_dyn2, b_dyn2, log_Q, eps,
                                h0, W_ic, b_ic, m_0, log_Q_0, eps0,
                                zo, kcl);
    kP2<<<512, 256, 0, stream>>>(zo, C, b_c, y, ms, kel);
    kR<<<1, 256, 0, stream>>>(kcl, kel, out);
}